// Round 5
// baseline (434.860 us; speedup 1.0000x reference)
//
#include <hip/hip_runtime.h>

#define DEV __device__ __forceinline__

typedef __attribute__((ext_vector_type(4))) float f32x4;
typedef __attribute__((ext_vector_type(8))) short s16x8;

DEV ushort f2b(float f) {
  union { float f; unsigned u; } x; x.f = f;
  unsigned r = (x.u + 0x7FFFu + ((x.u >> 16) & 1u)) >> 16;
  return (ushort)r;
}
DEV float b2f(ushort u) {
  union { unsigned u; float f; } x; x.u = ((unsigned)u) << 16;
  return x.f;
}

DEV void gload16(const ushort* g, ushort* l) {
  __builtin_amdgcn_global_load_lds(
      (const __attribute__((address_space(1))) unsigned int*)g,
      (__attribute__((address_space(3))) unsigned int*)l, 16, 0, 0);
}

struct PtrList { const float* p[4]; };

// ---------------- GEMM: C[M,N] = act((A[M,K] @ B[N,K]^T + bias) * scale) ----------------
// bf16 K-major A,B. 256 threads, 4 waves (2x2), BK=64, XOR-swizzled LDS (conflict-free).
// XCD-bijective chunk remap, x-major decode (B-panel locality per XCD L2; verified R15).
// NBUF=2: double-buffered prefetch loop. NBUF=1: m97-style single-buffer 2-barrier loop.
// BIAS: 0 none, 1 per-col, 2 per-row. ACT: 0/1 relu. OF/OB both false = stats-only.
// SKX>1: x encodes {ks, colblock}; K = chunk len; bf16 partial slice (z*SKX+ks)*sC -> Cb.
// CSTAT/RSTAT: per-col / per-row max+sumexp of this block's f32 acc -> pmo/pso.
template<int BM, int BN, int BIAS, int ACT, bool OF, bool OB, int SKX,
         bool CSTAT, bool RSTAT, int NBUF>
__global__ __launch_bounds__(256) void gemm(
    const ushort* __restrict__ A, int lda, long long sA,
    const ushort* __restrict__ B, int ldb, long long sB,
    float* __restrict__ Cf, ushort* __restrict__ Cb, int ldc, long long sC,
    const float* __restrict__ bias, const float* __restrict__ bias2,
    float* __restrict__ pmo, float* __restrict__ pso,
    float scale0, float scale1, int K)
{
  constexpr int WM = BM / 2, WN = BN / 2, FM = WM / 16, FN = WN / 16;
  __shared__ __align__(16) ushort As[NBUF][BM * 64];
  __shared__ __align__(16) ushort Bs[NBUF][BN * 64];
  const int tid = threadIdx.x, l = tid & 63, w = tid >> 6;
  const int wr = w >> 1, wc = w & 1;
  const int gx = gridDim.x, gy = gridDim.y;
  const int nwg = gx * gy;
  const int orig = blockIdx.y * gx + blockIdx.x;
  const int xcd = orig & 7, rest = orig >> 3;
  const int q8 = nwg >> 3, r8 = nwg & 7;
  const int f = (xcd < r8 ? xcd * (q8 + 1) : r8 * (q8 + 1) + (xcd - r8) * q8) + rest;
  int bxr = f / gy;
  const int byy = f - bxr * gy;
  int ks = 0;
  if constexpr (SKX > 1) {
    const int nbx = gx / SKX;
    ks = bxr / nbx; bxr -= ks * nbx;
  }
  const int brow = byy * BM, bcol = bxr * BN;
  const long long z = blockIdx.z;
  A += z * sA + (size_t)ks * K;
  B += z * sB + (size_t)ks * K;
  const int lr = l & 15;
  const int sw = lr & 7, kh = l >> 4;
  f32x4 acc[FM][FN] = {};
  const int nk = K >> 6;

  auto stage = [&](int kt, int buf) {
    const int kof = kt << 6;
#pragma unroll
    for (int i = 0; i < BM / 32; ++i) {
      const int c = i * 256 + tid;            // LDS chunk: row=c>>3, slot k8=c&7
      const int r = c >> 3, k8 = c & 7;
      gload16(A + (size_t)(brow + r) * lda + kof + ((k8 ^ (r & 7)) << 3),
              &As[buf][i * 2048 + w * 512]);
    }
#pragma unroll
    for (int i = 0; i < BN / 32; ++i) {
      const int c = i * 256 + tid;
      const int r = c >> 3, k8 = c & 7;
      gload16(B + (size_t)(bcol + r) * ldb + kof + ((k8 ^ (r & 7)) << 3),
              &Bs[buf][i * 2048 + w * 512]);
    }
  };

  auto compute = [&](int kt, int buf) {
#pragma unroll
    for (int kk = 0; kk < 2; ++kk) {
      const int koff = ((kk * 4 + kh) ^ sw) << 3;   // swizzled 16B-chunk offset
      s16x8 af[FM], bf[FN];
#pragma unroll
      for (int m = 0; m < FM; ++m)
        af[m] = *(const s16x8*)&As[buf][(wr * WM + m * 16 + lr) * 64 + koff];
#pragma unroll
      for (int n = 0; n < FN; ++n)
        bf[n] = *(const s16x8*)&Bs[buf][(wc * WN + n * 16 + lr) * 64 + koff];
#pragma unroll
      for (int m = 0; m < FM; ++m)
#pragma unroll
        for (int n = 0; n < FN; ++n)
          acc[m][n] = __builtin_amdgcn_mfma_f32_16x16x32_bf16(af[m], bf[n], acc[m][n], 0, 0, 0);
    }
  };

  if constexpr (NBUF == 2) {
    stage(0, 0);
    __syncthreads();
    for (int kt = 0; kt < nk - 1; ++kt) {
      stage(kt + 1, (kt + 1) & 1);
      compute(kt, kt & 1);
      __syncthreads();
    }
    compute(nk - 1, (nk - 1) & 1);
  } else {
    for (int kt = 0; kt < nk; ++kt) {
      stage(kt, 0);
      __syncthreads();   // staging complete (drains vmcnt)
      compute(kt, 0);
      __syncthreads();   // reads complete; buffer reusable
    }
  }

  if constexpr (OF || OB) {
    const float sc = (z == 0) ? scale0 : scale1;
    const float* bp = (z == 0) ? bias : bias2;
    const int cr = (l >> 4) * 4, cc = l & 15;
#pragma unroll
    for (int m = 0; m < FM; ++m) {
      const int r0 = brow + wr * WM + m * 16 + cr;
#pragma unroll
      for (int n = 0; n < FN; ++n) {
        const int gc = bcol + wc * WN + n * 16 + cc;
        float bc = 0.f;
        if constexpr (BIAS == 1) bc = bp[gc];
#pragma unroll
        for (int j = 0; j < 4; ++j) {
          float v = acc[m][n][j];
          if constexpr (BIAS == 1) v += bc;
          if constexpr (BIAS == 2) v += bp[r0 + j];
          v *= sc;
          if constexpr (ACT == 1) v = fmaxf(v, 0.f);
          const size_t off = (size_t)(r0 + j) * ldc + gc + (size_t)((z * SKX + ks) * sC);
          if constexpr (OF) Cf[off] = v;
          if constexpr (OB) Cb[off] = f2b(v);
        }
      }
    }
  }

  if constexpr (CSTAT) {
    __shared__ float sM[2][2][FN][16], sS[2][2][FN][16];
    float mx[FN], se[FN];
#pragma unroll
    for (int n = 0; n < FN; ++n) {
      float m0 = -3e38f;
#pragma unroll
      for (int m = 0; m < FM; ++m)
#pragma unroll
        for (int j = 0; j < 4; ++j) m0 = fmaxf(m0, acc[m][n][j]);
      float s0 = 0.f;
#pragma unroll
      for (int m = 0; m < FM; ++m)
#pragma unroll
        for (int j = 0; j < 4; ++j) s0 += __expf(acc[m][n][j] - m0);
      mx[n] = m0; se[n] = s0;
    }
#pragma unroll
    for (int o = 16; o <= 32; o <<= 1) {
#pragma unroll
      for (int n = 0; n < FN; ++n) {
        float m2 = __shfl_xor(mx[n], o), s2 = __shfl_xor(se[n], o);
        float M = fmaxf(mx[n], m2);
        se[n] = se[n] * __expf(mx[n] - M) + s2 * __expf(m2 - M);
        mx[n] = M;
      }
    }
    __syncthreads();
    if (l < 16) {
#pragma unroll
      for (int n = 0; n < FN; ++n) { sM[wr][wc][n][l] = mx[n]; sS[wr][wc][n][l] = se[n]; }
    }
    __syncthreads();
    if (wr == 0 && l < 16) {
#pragma unroll
      for (int n = 0; n < FN; ++n) {
        float m1 = sM[0][wc][n][l], m2 = sM[1][wc][n][l];
        float s1 = sS[0][wc][n][l], s2 = sS[1][wc][n][l];
        float M = fmaxf(m1, m2);
        float S = s1 * __expf(m1 - M) + s2 * __expf(m2 - M);
        const int gc = bcol + wc * 32 + n * 16 + l;
        const size_t o = ((size_t)(z * gy + byy)) * 2048 + gc;
        pmo[o] = M; pso[o] = S;
      }
    }
  }

  if constexpr (RSTAT) {
    __shared__ float sRM[2][2][WM], sRS[2][2][WM];
#pragma unroll
    for (int m = 0; m < FM; ++m) {
#pragma unroll
      for (int j = 0; j < 4; ++j) {
        float m0 = -3e38f;
#pragma unroll
        for (int n = 0; n < FN; ++n) m0 = fmaxf(m0, acc[m][n][j]);
        float s0 = 0.f;
#pragma unroll
        for (int n = 0; n < FN; ++n) s0 += __expf(acc[m][n][j] - m0);
#pragma unroll
        for (int o = 1; o <= 8; o <<= 1) {
          float m2 = __shfl_xor(m0, o), s2 = __shfl_xor(s0, o);
          float M = fmaxf(m0, m2);
          s0 = s0 * __expf(m0 - M) + s2 * __expf(m2 - M);
          m0 = M;
        }
        if ((l & 15) == 0) {
          sRM[wr][wc][m * 16 + (l >> 4) * 4 + j] = m0;
          sRS[wr][wc][m * 16 + (l >> 4) * 4 + j] = s0;
        }
      }
    }
    __syncthreads();
    if (wc == 0) {
      float m1 = sRM[wr][0][l], m2 = sRM[wr][1][l];
      float s1 = sRS[wr][0][l], s2 = sRS[wr][1][l];
      float M = fmaxf(m1, m2);
      float S = s1 * __expf(m1 - M) + s2 * __expf(m2 - M);
      const size_t o = (size_t)bxr * 2048 + brow + wr * WM + l;
      pmo[o] = M; pso[o] = S;
    }
  }
}

// ================= 256x256 8-phase GEMM, read-ahead + compiler-scheduled waits ==========
// (R4 best variant, unchanged: 39.6-40.0 us, ~807 TF effective. Further schedule surgery
// shelved after 4 null results; MFMA floor at this shape/occupancy is ~16.6 us.)
template<int MH, int NH>
DEV void qmfma2(const s16x8 (&Ax)[8], const s16x8 (&Bf)[4], f32x4 (&acc)[8][4]) {
#pragma unroll
  for (int kk = 0; kk < 2; ++kk)
#pragma unroll
    for (int m = 0; m < 4; ++m)
#pragma unroll
      for (int n = 0; n < 2; ++n)
        acc[MH * 4 + m][NH * 2 + n] = __builtin_amdgcn_mfma_f32_16x16x32_bf16(
            Ax[kk * 4 + m], Bf[kk * 2 + n], acc[MH * 4 + m][NH * 2 + n], 0, 0, 0);
}

DEV void tailwait(int c) {
  if (c == 1) { asm volatile("s_waitcnt vmcnt(4)" ::: "memory"); }
  else if (c == 2) { asm volatile("s_waitcnt vmcnt(0)" ::: "memory"); }
}

#define GBAR() asm volatile("s_barrier" ::: "memory")

template<int NBX>
__global__ __launch_bounds__(512, 2) void gemm256(
    const ushort* __restrict__ A, int lda,
    const ushort* __restrict__ B, int ldb,
    ushort* __restrict__ Cb, int ldc, long long sC, int Kc)
{
  __shared__ __align__(16) ushort As[2][2][8192];   // [buf][half][128*64]
  __shared__ __align__(16) ushort Bs[2][2][8192];
  const int tid = threadIdx.x, l = tid & 63, w = tid >> 6;
  const int wr = w >> 2, wc = w & 3;
  const int gx = gridDim.x, gy = gridDim.y;
  const int nwg = gx * gy;
  const int orig = blockIdx.y * gx + blockIdx.x;
  const int xcd = orig & 7, rest = orig >> 3;
  const int q8 = nwg >> 3, r8 = nwg & 7;
  const int f = (xcd < r8 ? xcd * (q8 + 1) : r8 * (q8 + 1) + (xcd - r8) * q8) + rest;
  int bxr = f / gy;
  const int byy = f - bxr * gy;
  const int ks = bxr / NBX; bxr -= ks * NBX;
  const int brow = byy * 256, bcol = bxr * 256;
  A += (size_t)ks * Kc;
  B += (size_t)ks * Kc;
  const int nk = Kc >> 6;
  const int lr = l & 15, kh = l >> 4, sw = lr & 7;
  const int arow = wr * 64 + lr, brw = wc * 32 + lr;

  // staging: chunk c = i*512+tid; i=0 -> rows 0..63 of the half, i=1 -> rows 64..127
  const int r0 = tid >> 3, k80 = tid & 7;
  const size_t aoff = (size_t)(brow + r0) * lda + ((k80 ^ (r0 & 7)) << 3);
  const size_t boff = (size_t)(bcol + r0) * ldb + ((k80 ^ (r0 & 7)) << 3);

  f32x4 acc[8][4] = {};
  s16x8 Ax[8];              // active A-half fragments (single slot)
  s16x8 B0s[4], B1s[4];     // B-half fragments, both halves of active buffer

  auto stA = [&](int kt, int buf, int half) {
    if (kt >= nk) return;
    const ushort* s = A + aoff + (size_t)(half * 128) * lda + (kt << 6);
    gload16(s, &As[buf][half][w * 512]);
    gload16(s + (size_t)64 * lda, &As[buf][half][4096 + w * 512]);
  };
  auto stB = [&](int kt, int buf, int half) {
    if (kt >= nk) return;
    const ushort* s = B + boff + (size_t)(half * 128) * ldb + (kt << 6);
    gload16(s, &Bs[buf][half][w * 512]);
    gload16(s + (size_t)64 * ldb, &Bs[buf][half][4096 + w * 512]);
  };
  auto rdA = [&](int buf, int half) {
#pragma unroll
    for (int kk = 0; kk < 2; ++kk) {
      const int koff = ((kk * 4 + kh) ^ sw) << 3;
#pragma unroll
      for (int m = 0; m < 4; ++m)
        Ax[kk * 4 + m] = *(const s16x8*)&As[buf][half][(arow + m * 16) * 64 + koff];
    }
  };
  auto rdB = [&](s16x8 (&dst)[4], int buf, int half) {
#pragma unroll
    for (int kk = 0; kk < 2; ++kk) {
      const int koff = ((kk * 4 + kh) ^ sw) << 3;
#pragma unroll
      for (int n = 0; n < 2; ++n)
        dst[kk * 2 + n] = *(const s16x8*)&Bs[buf][half][(brw + n * 16) * 64 + koff];
    }
  };

  // prologue: tile0 {A0,B0,A1,B1} -> buf0; tile1 {A0,B0} -> buf1 (12 loads)
  stA(0, 0, 0); stB(0, 0, 0); stA(0, 0, 1); stB(0, 0, 1);
  stA(1, 1, 0); stB(1, 1, 0);
  asm volatile("s_waitcnt vmcnt(4)" ::: "memory");   // tile0 landed; tile1 A0/B0 in flight
  GBAR();
  rdA(0, 0); rdB(B0s, 0, 0);                          // frags for P1 of iter 0

  const int NT2 = nk >> 1;
#pragma unroll 1
  for (int j = 0; j < NT2; ++j) {
    const int tb = 2 * j + 1, ta2 = 2 * j + 2, tb2 = 2 * j + 3;
    const bool more = (ta2 < nk);
    // P1: MFMA(A0,B0)@buf0; read-ahead B1@buf0 under the MFMA
    stA(tb, 1, 1); GBAR();
    rdB(B1s, 0, 1);
    __builtin_amdgcn_s_setprio(1); qmfma2<0, 0>(Ax, B0s, acc); __builtin_amdgcn_s_setprio(0);
    GBAR();
    // P2: MFMA(A0,B1)
    stB(tb, 1, 1); GBAR();
    __builtin_amdgcn_s_setprio(1); qmfma2<0, 1>(Ax, B1s, acc); __builtin_amdgcn_s_setprio(0);
    GBAR();
    // P3: in-phase A-half1 read, then MFMA(A1,B0)
    stA(ta2, 0, 0); GBAR();
    rdA(0, 1);
    __builtin_amdgcn_s_setprio(1); qmfma2<1, 0>(Ax, B0s, acc); __builtin_amdgcn_s_setprio(0);
    GBAR();
    // P4: MFMA(A1,B1); counted vmcnt; then GAP reads of b's A0/B0 (all-waves safe)
    stB(ta2, 0, 0); GBAR();
    __builtin_amdgcn_s_setprio(1); qmfma2<1, 1>(Ax, B1s, acc); __builtin_amdgcn_s_setprio(0);
    tailwait(more ? 1 : 2); GBAR();
    rdA(1, 0); rdB(B0s, 1, 0);
    // P5: MFMA(A0,B0)@buf1; read-ahead B1@buf1
    stA(ta2, 0, 1); GBAR();
    rdB(B1s, 1, 1);
    __builtin_amdgcn_s_setprio(1); qmfma2<0, 0>(Ax, B0s, acc); __builtin_amdgcn_s_setprio(0);
    GBAR();
    // P6: MFMA(A0,B1)
    stB(ta2, 0, 1); GBAR();
    __builtin_amdgcn_s_setprio(1); qmfma2<0, 1>(Ax, B1s, acc); __builtin_amdgcn_s_setprio(0);
    GBAR();
    // P7: in-phase A-half1 read, then MFMA(A1,B0)
    stA(tb2, 1, 0); GBAR();
    rdA(1, 1);
    __builtin_amdgcn_s_setprio(1); qmfma2<1, 0>(Ax, B0s, acc); __builtin_amdgcn_s_setprio(0);
    GBAR();
    // P8: MFMA(A1,B1); counted vmcnt; GAP reads of (a+2)'s A0/B0 for next P1
    stB(tb2, 1, 0); GBAR();
    __builtin_amdgcn_s_setprio(1); qmfma2<1, 1>(Ax, B1s, acc); __builtin_amdgcn_s_setprio(0);
    tailwait(more ? 1 : 0); GBAR();
    if (more) { rdA(0, 0); rdB(B0s, 0, 0); }
  }

  // epilogue: bf16 partial slice ks
  ushort* out = Cb + (size_t)ks * sC;
  const int cr = kh * 4, cc = lr;
#pragma unroll
  for (int mh = 0; mh < 2; ++mh)
#pragma unroll
    for (int m = 0; m < 4; ++m) {
      const int ro = brow + mh * 128 + wr * 64 + m * 16 + cr;
#pragma unroll
      for (int nh = 0; nh < 2; ++nh)
#pragma unroll
        for (int n = 0; n < 2; ++n) {
          const int gc = bcol + nh * 128 + wc * 32 + n * 16 + cc;
#pragma unroll
          for (int j2 = 0; j2 < 4; ++j2)
            out[(size_t)(ro + j2) * ldc + gc] = f2b(acc[mh * 4 + m][nh * 2 + n][j2]);
        }
    }
}

// ---------------- fused FFN: Y[r, bx*64+c] = relu(X@W1^T+b1) @ W2chunk^T + b2 ----------
// grid (8 out-col chunks, 32 row blocks), 256 thr, 64x64 tiles, 4 waves (2x2).
// H kept in LDS with the stage-compatible XOR swizzle; f32 accumulation throughout.
__global__ __launch_bounds__(256) void ffn_fused(
    const ushort* __restrict__ X, const ushort* __restrict__ W1,
    const float* __restrict__ b1, const ushort* __restrict__ W2T,
    const float* __restrict__ b2, float* __restrict__ Y)
{
  __shared__ __align__(16) ushort As[64 * 64];
  __shared__ __align__(16) ushort Bs[64 * 64];
  __shared__ __align__(16) ushort Hs[64 * 64];
  const int tid = threadIdx.x, l = tid & 63, w = tid >> 6;
  const int wr = w >> 1, wc = w & 1;
  const int bx = blockIdx.x, brow = blockIdx.y * 64;
  const int lr = l & 15, g = l >> 4, sw = lr & 7;
  f32x4 acc[2][2] = {};
  // phase 1: H = relu(X[64,512] @ W1[64,512]^T + b1)
  for (int kt = 0; kt < 8; ++kt) {
    const int kof = kt << 6;
#pragma unroll
    for (int i = 0; i < 2; ++i) {
      const int c = i * 256 + tid, r = c >> 3, k8 = c & 7;
      gload16(X + (size_t)(brow + r) * 512 + kof + ((k8 ^ (r & 7)) << 3),
              &As[i * 2048 + w * 512]);
    }
#pragma unroll
    for (int i = 0; i < 2; ++i) {
      const int c = i * 256 + tid, r = c >> 3, k8 = c & 7;
      gload16(W1 + (size_t)r * 512 + kof + ((k8 ^ (r & 7)) << 3),
              &Bs[i * 2048 + w * 512]);
    }
    __syncthreads();
#pragma unroll
    for (int kk = 0; kk < 2; ++kk) {
      const int koff = ((kk * 4 + g) ^ sw) << 3;
      s16x8 af[2], bf[2];
#pragma unroll
      for (int m = 0; m < 2; ++m) af[m] = *(const s16x8*)&As[(wr * 32 + m * 16 + lr) * 64 + koff];
#pragma unroll
      for (int n = 0; n < 2; ++n) bf[n] = *(const s16x8*)&Bs[(wc * 32 + n * 16 + lr) * 64 + koff];
#pragma unroll
      for (int m = 0; m < 2; ++m)
#pragma unroll
        for (int n = 0; n < 2; ++n)
          acc[m][n] = __builtin_amdgcn_mfma_f32_16x16x32_bf16(af[m], bf[n], acc[m][n], 0, 0, 0);
    }
    __syncthreads();
  }
  // epilogue1: bias+relu -> Hs (swizzled: content[row][s] = H[row][col], s=(col>>3)^(row&7))
#pragma unroll
  for (int m = 0; m < 2; ++m)
#pragma unroll
    for (int n = 0; n < 2; ++n) {
      const int col = wc * 32 + n * 16 + lr;
      const float bb = b1[col];
#pragma unroll
      for (int j = 0; j < 4; ++j) {
        const int row = wr * 32 + m * 16 + g * 4 + j;
        Hs[row * 64 + (((col >> 3) ^ (row & 7)) << 3) + (col & 7)] =
            f2b(fmaxf(acc[m][n][j] + bb, 0.f));
      }
    }
  // stage W2 chunk (Bs free after the final loop barrier)
#pragma unroll
  for (int i = 0; i < 2; ++i) {
    const int c = i * 256 + tid, r = c >> 3, k8 = c & 7;
    gload16(W2T + (size_t)(bx * 64 + r) * 64 + ((k8 ^ (r & 7)) << 3),
            &Bs[i * 2048 + w * 512]);
  }
  __syncthreads();
  // phase 2: Y = H @ W2chunk^T + b2 (K=64)
  f32x4 acc2[2][2] = {};
#pragma unroll
  for (int kk = 0; kk < 2; ++kk) {
    const int koff = ((kk * 4 + g) ^ sw) << 3;
    s16x8 af[2], bf[2];
#pragma unroll
    for (int m = 0; m < 2; ++m) af[m] = *(const s16x8*)&Hs[(wr * 32 + m * 16 + lr) * 64 + koff];
#pragma unroll
    for (int n = 0; n < 2; ++n) bf[n] = *(const s16x8*)&Bs[(wc * 32 + n * 16 + lr) * 64 + koff];
#pragma unroll
    for (int m = 0; m < 2; ++m)
#pragma unroll
      for (int n = 0; n < 2; ++n)
        acc2[m][n] = __builtin_amdgcn_mfma_f32_16x16x32_bf16(af[m], bf[n], acc2[m][n], 0, 0, 0);
  }
#pragma unroll
  for (int m = 0; m < 2; ++m)
#pragma unroll
    for (int n = 0; n < 2; ++n) {
      const int gc = bx * 64 + wc * 32 + n * 16 + lr;
      const float bb = b2[gc];
#pragma unroll
      for (int j = 0; j < 4; ++j) {
        const int row = brow + wr * 32 + m * 16 + g * 4 + j;
        Y[(size_t)row * 512 + gc] = acc2[m][n][j] + bb;
      }
    }
}

// ---------------- fused type-A PV, m-split x4: bf16 partial ZA over 8 m-chunks ----------
__global__ __launch_bounds__(256) void pv_fused(
    const ushort* __restrict__ Q, const ushort* __restrict__ K,
    const ushort* __restrict__ Vt, const float* __restrict__ lse,
    ushort* __restrict__ ZAP)
{
  __shared__ __align__(16) ushort Qs[64 * 64];
  __shared__ __align__(16) ushort Ks[2][64 * 64];
  __shared__ __align__(16) ushort Vs[2][64 * 64];
  __shared__ __align__(16) ushort Ps[64 * 64];
  __shared__ float Ls[512];
  const int tid = threadIdx.x, l = tid & 63, w = tid >> 6;
  const int wr = w >> 1, wc = w & 1;
  const int h = blockIdx.z, brow = blockIdx.x * 64, ms = blockIdx.y;
  const int lr = l & 15, g = l >> 4, sw = lr & 7;

  auto stageKV = [&](int mc, int buf) {
#pragma unroll
    for (int i = 0; i < 2; ++i) {
      const int c = i * 256 + tid, r = c >> 3, k8 = c & 7;
      gload16(K + (size_t)(mc * 64 + r) * 512 + h * 64 + ((k8 ^ (r & 7)) << 3),
              &Ks[buf][i * 2048 + w * 512]);
    }
#pragma unroll
    for (int i = 0; i < 2; ++i) {
      const int c = i * 256 + tid, r = c >> 3, k8 = c & 7;
      gload16(Vt + (size_t)(h * 64 + r) * 2048 + mc * 64 + ((k8 ^ (r & 7)) << 3),
              &Vs[buf][i * 2048 + w * 512]);
    }
  };

#pragma unroll
  for (int i = 0; i < 2; ++i) {
    const int c = i * 256 + tid, r = c >> 3, k8 = c & 7;
    gload16(Q + (size_t)(brow + r) * 512 + h * 64 + ((k8 ^ (r & 7)) << 3),
            &Qs[i * 2048 + w * 512]);
  }
  stageKV(ms * 8, 0);
  for (int i = tid; i < 512; i += 256) Ls[i] = lse[h * 2048 + ms * 512 + i];
  __syncthreads();

  s16x8 aq[2][2];
#pragma unroll
  for (int nf = 0; nf < 2; ++nf)
#pragma unroll
    for (int kk = 0; kk < 2; ++kk)
      aq[nf][kk] = *(const s16x8*)&Qs[(wr * 32 + nf * 16 + lr) * 64 + (((kk * 4 + g) ^ sw) << 3)];

  f32x4 zacc[2][2] = {};
  for (int mi = 0; mi < 8; ++mi) {
    const int mc = ms * 8 + mi;
    const int buf = mi & 1;
    if (mi < 7) stageKV(mc + 1, buf ^ 1);
    f32x4 sacc[2][2] = {};
#pragma unroll
    for (int kk = 0; kk < 2; ++kk) {
      const int koff = ((kk * 4 + g) ^ sw) << 3;
      s16x8 bk[2];
#pragma unroll
      for (int mf = 0; mf < 2; ++mf)
        bk[mf] = *(const s16x8*)&Ks[buf][(wc * 32 + mf * 16 + lr) * 64 + koff];
#pragma unroll
      for (int nf = 0; nf < 2; ++nf)
#pragma unroll
        for (int mf = 0; mf < 2; ++mf)
          sacc[nf][mf] = __builtin_amdgcn_mfma_f32_16x16x32_bf16(aq[nf][kk], bk[mf], sacc[nf][mf], 0, 0, 0);
    }
#pragma unroll
    for (int nf = 0; nf < 2; ++nf)
#pragma unroll
      for (int mf = 0; mf < 2; ++mf) {
        const int m_loc = wc * 32 + mf * 16 + lr;
        const float lv = Ls[mi * 64 + m_loc];
#pragma unroll
        for (int j = 0; j < 4; ++j) {
          const int n_loc = wr * 32 + nf * 16 + g * 4 + j;
          Ps[n_loc * 64 + (((m_loc >> 3) ^ (n_loc & 7)) << 3) + (m_loc & 7)] =
              f2b(__expf(sacc[nf][mf][j] - lv));
        }
      }
    __syncthreads();  // P complete (also drains KV prefetch)
#pragma unroll
    for (int kk = 0; kk < 2; ++kk) {
      const int koff = ((kk * 4 + g) ^ sw) << 3;
      s16x8 pa[2], bv[2];
#pragma unroll
      for (int nf = 0; nf < 2; ++nf)
        pa[nf] = *(const s16x8*)&Ps[(wr * 32 + nf * 16 + lr) * 64 + koff];
#pragma unroll
      for (int vf = 0; vf < 2; ++vf)
        bv[vf] = *(const s16x8*)&Vs[buf][(wc * 32 + vf * 16 + lr) * 64 + koff];
#pragma unroll
      for (int nf = 0; nf < 2; ++nf)
#pragma unroll
        for (int vf = 0; vf < 2; ++vf)
          zacc[nf][vf] = __builtin_amdgcn_mfma_f32_16x16x32_bf16(pa[nf], bv[vf], zacc[nf][vf], 0, 0, 0);
    }
    __syncthreads();
  }
  ushort* out = ZAP + (size_t)ms * 2048 * 512;
#pragma unroll
  for (int nf = 0; nf < 2; ++nf)
#pragma unroll
    for (int vf = 0; vf < 2; ++vf)
#pragma unroll
      for (int j = 0; j < 4; ++j) {
        const int n = brow + wr * 32 + nf * 16 + g * 4 + j;
        const int col = h * 64 + wc * 32 + vf * 16 + lr;
        out[(size_t)n * 512 + col] = f2b(zacc[nf][vf][j]);
      }
}

// ===== fused exp+PV for encoder attention: ATT[m,n] = sum_k exp(S[m,k]-LSE[m])*Vt[n,k] ==
// Replaces expconv_row + ATTP gemm + reduceN (~50 MB HBM round-trips/layer). P fragments
// built IN REGISTERS: lane l's A-frag for (m,kk) = row lr(+m*16), contiguous k-chunk
// (kk*4+kh)*8 — exactly the content the LDS-swizzle reader delivers in gemm (proven
// layout). V staged via standard swizzled global_load_lds, double-buffered. ONE barrier
// per K-tile; stage(kt+1) placed AFTER MFMA(kt): between barrier(kt) and barrier(kt+1)
// only Bs[buf] is read and only Bs[buf^1] written -> race-free; barrier's implicit
// vmcnt(0) drain guarantees Bs[buf] landed. Numerics identical to the old path
// (f32 S, f32 LSE, __expf, f2b).
__global__ __launch_bounds__(256) void attp_fused(
    const float* __restrict__ S, const float* __restrict__ lse,
    const ushort* __restrict__ Vt, ushort* __restrict__ out)
{
  __shared__ __align__(16) ushort Bs[2][64 * 64];
  const int tid = threadIdx.x, l = tid & 63, w = tid >> 6;
  const int wr = w >> 1, wc = w & 1;
  const int gx = gridDim.x, gy = gridDim.y;
  const int nwg = gx * gy;
  const int orig = blockIdx.y * gx + blockIdx.x;
  const int xcd = orig & 7, rest = orig >> 3;
  const int q8 = nwg >> 3, r8 = nwg & 7;
  const int f = (xcd < r8 ? xcd * (q8 + 1) : r8 * (q8 + 1) + (xcd - r8) * q8) + rest;
  const int bxr = f / gy;
  const int byy = f - bxr * gy;
  const int brow = byy * 64, bcol = bxr * 64;
  const int lr = l & 15, kh = l >> 4, sw = lr & 7;
  f32x4 acc[2][2] = {};
  const float Lm0 = lse[brow + wr * 32 + lr];
  const float Lm1 = lse[brow + wr * 32 + 16 + lr];

  auto stageB = [&](int kt, int buf) {
    const int kof = kt << 6;
#pragma unroll
    for (int i = 0; i < 2; ++i) {
      const int c = i * 256 + tid, r = c >> 3, k8 = c & 7;
      gload16(Vt + (size_t)(bcol + r) * 2048 + kof + ((k8 ^ (r & 7)) << 3),
              &Bs[buf][i * 2048 + w * 512]);
    }
  };

  stageB(0, 0);
#pragma unroll 1
  for (int kt = 0; kt < 32; ++kt) {
    const int buf = kt & 1;
    // build P fragments in registers (overlaps in-flight V staging)
    s16x8 pa[2][2];
#pragma unroll
    for (int m = 0; m < 2; ++m) {
      const float L = (m == 0) ? Lm0 : Lm1;
      const size_t rb = (size_t)(brow + wr * 32 + m * 16 + lr) * 2048 + (kt << 6) + kh * 8;
#pragma unroll
      for (int kk = 0; kk < 2; ++kk) {
        float4 v0 = *(const float4*)(S + rb + kk * 32);
        float4 v1 = *(const float4*)(S + rb + kk * 32 + 4);
        s16x8 t;
        t[0] = (short)f2b(__expf(v0.x - L)); t[1] = (short)f2b(__expf(v0.y - L));
        t[2] = (short)f2b(__expf(v0.z - L)); t[3] = (short)f2b(__expf(v0.w - L));
        t[4] = (short)f2b(__expf(v1.x - L)); t[5] = (short)f2b(__expf(v1.y - L));
        t[6] = (short)f2b(__expf(v1.z - L)); t[7] = (short)f2b(__expf(v1.w - L));
        pa[m][kk] = t;
      }
    }
    __syncthreads();   // Bs[buf] landed (vmcnt drain); prev MFMA done with Bs[buf^1]
#pragma unroll
    for (int kk = 0; kk < 2; ++kk) {
      const int koff = ((kk * 4 + kh) ^ sw) << 3;
      s16x8 bf[2];
#pragma unroll
      for (int n = 0; n < 2; ++n)
        bf[n] = *(const s16x8*)&Bs[buf][(wc * 32 + n * 16 + lr) * 64 + koff];
#pragma unroll
      for (int m = 0; m < 2; ++m)
#pragma unroll
        for (int n = 0; n < 2; ++n)
          acc[m][n] = __builtin_amdgcn_mfma_f32_16x16x32_bf16(pa[m][kk], bf[n], acc[m][n], 0, 0, 0);
    }
    if (kt < 31) stageB(kt + 1, buf ^ 1);   // write-side buf^1: race-free in this window
  }

  const int cr = kh * 4, cc = lr;
#pragma unroll
  for (int m = 0; m < 2; ++m)
#pragma unroll
    for (int n = 0; n < 2; ++n) {
      const int gc = bcol + wc * 32 + n * 16 + cc;
#pragma unroll
      for (int j = 0; j < 4; ++j)
        out[(size_t)(brow + wr * 32 + m * 16 + cr + j) * 512 + gc] = f2b(acc[m][n][j]);
    }
}

// ---- rowcombine: LSE[r] from 32 per-col-chunk (max,sumexp) stats (PM/PS: [32][2048]) ----
__global__ __launch_bounds__(256) void rowcombine(const float* __restrict__ pm,
    const float* __restrict__ ps, float* __restrict__ lse) {
  const int r = blockIdx.x * 256 + threadIdx.x;
  float M = -3e38f;
#pragma unroll
  for (int s = 0; s < 32; ++s) M = fmaxf(M, pm[(size_t)s * 2048 + r]);
  float S = 0.f;
#pragma unroll
  for (int s = 0; s < 32; ++s) {
    const size_t o = (size_t)s * 2048 + r;
    S += ps[o] * __expf(pm[o] - M);
  }
  lse[r] = M + __logf(S);
}

// ------- split-K reduce: sum NS bf16 slices (f32 accum) -> bf16; optional bias+relu -----
template<int NS, int ACT>
__global__ __launch_bounds__(256) void reduceN(const ushort* __restrict__ P, long long sC,
    ushort* __restrict__ out, int cols, int ldout, long long zPoff, long long zOoff,
    int cshift, long long bstride, float scale, int scThresh, int rows,
    const float* __restrict__ bias)
{
  P += blockIdx.z * zPoff; out += blockIdx.z * zOoff;
  const int c4n = cols >> 2;
  const size_t total = (size_t)rows * c4n;
  for (size_t i = (size_t)blockIdx.x * 256 + threadIdx.x; i < total; i += (size_t)gridDim.x * 256) {
    const size_t r = i / c4n;
    const int c4 = (int)(i - r * c4n) << 2;
    float4 s = make_float4(0.f, 0.f, 0.f, 0.f);
#pragma unroll
    for (int k = 0; k < NS; ++k) {
      ushort4 t = *(const ushort4*)(P + (size_t)k * sC + r * cols + c4);
      s.x += b2f(t.x); s.y += b2f(t.y); s.z += b2f(t.z); s.w += b2f(t.w);
    }
    if constexpr (ACT == 1) {
      float4 bb = *(const float4*)(bias + c4);
      s.x = fmaxf(s.x + bb.x, 0.f); s.y = fmaxf(s.y + bb.y, 0.f);
      s.z = fmaxf(s.z + bb.z, 0.f); s.w = fmaxf(s.w + bb.w, 0.f);
    }
    const float sc = (c4 < scThresh) ? scale : 1.f;
    ushort4 o;
    o.x = f2b(s.x * sc); o.y = f2b(s.y * sc); o.z = f2b(s.z * sc); o.w = f2b(s.w * sc);
    const size_t oo = r * ldout + (size_t)(c4 >> cshift) * bstride + (c4 & ((1 << cshift) - 1));
    *(ushort4*)(out + oo) = o;
  }
}

// ---------------- prep A: XAb = bf16(X1|X2) (phase 0) ----------------
__global__ __launch_bounds__(256) void prep_xab(const float* __restrict__ X1,
    const float* __restrict__ X2, ushort* __restrict__ XAb) {
  const size_t total = (size_t)2048 * 1280;       // ushort4 units (5120/4)
  for (size_t i = (size_t)blockIdx.x * 256 + threadIdx.x; i < total; i += (size_t)gridDim.x * 256) {
    const size_t r = i / 1280;
    const int c = (int)(i - r * 1280) << 2;
    float4 v = (c < 4096) ? *(const float4*)(X1 + r * 4096 + c)
                          : *(const float4*)(X2 + r * 1024 + (c - 4096));
    ushort4 o; o.x = f2b(v.x); o.y = f2b(v.y); o.z = f2b(v.z); o.w = f2b(v.w);
    *(ushort4*)(XAb + r * 5120 + c) = o;
  }
}

// ---- prep B: sX3 = bf16(sigmoid(X3)); Walib = bf16(Wali). MUST run after phase-A
//      partials (QKVP/ZBP, which overlap these arena spans) are consumed. ----
__global__ __launch_bounds__(256) void prep_x3w(const float* __restrict__ X3,
    const float* __restrict__ Wali, ushort* __restrict__ sX3,
    ushort* __restrict__ Walib) {
  const size_t n1 = (size_t)2048 * 1024;          // sX3 (4096/4)
  const size_t n2 = (size_t)4096 * 512;           // Walib (2048/4)
  const size_t total = n1 + n2;
  for (size_t i = (size_t)blockIdx.x * 256 + threadIdx.x; i < total; i += (size_t)gridDim.x * 256) {
    if (i < n1) {
      const size_t r = i / 1024;
      const int c = (int)(i - r * 1024) << 2;
      float4 v = *(const float4*)(X3 + r * 4096 + c);
      v.x = 1.f / (1.f + __expf(-v.x)); v.y = 1.f / (1.f + __expf(-v.y));
      v.z = 1.f / (1.f + __expf(-v.z)); v.w = 1.f / (1.f + __expf(-v.w));
      ushort4 o; o.x = f2b(v.x); o.y = f2b(v.y); o.z = f2b(v.z); o.w = f2b(v.w);
      *(ushort4*)(sX3 + r * 4096 + c) = o;
    } else {
      const size_t j = i - n1;
      const size_t r = j / 512;
      const int c = (int)(j - r * 512) << 2;
      float4 v = *(const float4*)(Wali + r * 2048 + c);
      ushort4 o; o.x = f2b(v.x); o.y = f2b(v.y); o.z = f2b(v.z); o.w = f2b(v.w);
      *(ushort4*)(Walib + r * 2048 + c) = o;
    }
  }
}

__global__ __launch_bounds__(256) void colcombine(const float* __restrict__ pm,
    const float* __restrict__ ps, float* __restrict__ lse) {
  const int id = blockIdx.x * 256 + threadIdx.x;  // h*2048 + c
  const int h = id >> 11, c = id & 2047;
  float M = -3e38f;
#pragma unroll
  for (int s = 0; s < 16; ++s) M = fmaxf(M, pm[((size_t)(h * 16 + s)) * 2048 + c]);
  float S = 0.f;
#pragma unroll
  for (int s = 0; s < 16; ++s) {
    size_t o = ((size_t)(h * 16 + s)) * 2048 + c;
    S += ps[o] * __expf(pm[o] - M);
  }
  lse[id] = M + __logf(S);
}

// ---------------- multi-tensor transpose_conv: z selects tensor (z/zPerT) + slice --------
__global__ __launch_bounds__(256) void transpose_conv_multi(PtrList in, int zPerT,
    ushort* __restrict__ out, int R, int C) {
  __shared__ ushort t[32][33];
  const int z = blockIdx.z;
  const float* ip = in.p[z / zPerT] + (size_t)(z % zPerT) * R * C;
  ushort* op = out + (size_t)z * R * C;
  const int r0 = blockIdx.x * 32, c0 = blockIdx.y * 32;
#pragma unroll
  for (int i = 0; i < 4; ++i) {
    int r = r0 + threadIdx.y + i * 8;
    int c = c0 + threadIdx.x;
    float v = (r < R && c < C) ? ip[(size_t)r * C + c] : 0.f;
    t[threadIdx.x][threadIdx.y + i * 8] = f2b(v);
  }
  __syncthreads();
#pragma unroll
  for (int i = 0; i < 4; ++i) {
    int c = c0 + threadIdx.y + i * 8;
    int r = r0 + threadIdx.x;
    if (c < C && r < R) op[(size_t)c * R + r] = t[threadIdx.y + i * 8][threadIdx.x];
  }
}

// ---------------- batched small transposes: WVB, W_O, eW1, eW2 in one launch ------------
__global__ __launch_bounds__(256) void transpose_conv_batch(
    const float* __restrict__ WVB, ushort* __restrict__ WVBT,
    const float* __restrict__ W_O, ushort* __restrict__ WOT,
    const float* __restrict__ eW1, ushort* __restrict__ EW1T,
    const float* __restrict__ eW2, ushort* __restrict__ EW2T) {
  __shared__ ushort t[32][33];
  const int b = blockIdx.x;
  const float* ip; ushort* op; int R, C, r0, c0;
  if (b < 256) {
    const int h = b >> 6, loc = b & 63;
    ip = WVB + (size_t)h * 65536; op = WVBT + (size_t)h * 65536;
    R = 1024; C = 64; r0 = (loc & 31) * 32; c0 = (loc >> 5) * 32;
  } else if (b < 640) {
    const int loc = b - 256;
    ip = W_O; op = WOT;
    R = 768; C = 512; r0 = (loc % 24) * 32; c0 = (loc / 24) * 32;
  } else if (b < 704) {
    const int loc = b - 640, lyr = loc >> 5, lo = loc & 31;
    ip = eW1 + (size_t)lyr * 32768; op = EW1T + (size_t)lyr * 32768;
    R = 512; C = 64; r0 = (lo & 15) * 32; c0 = (lo >> 4) * 32;
  } else {
    const int loc = b - 704, lyr = loc >> 5, lo = loc & 31;
    ip = eW2 + (size_t)lyr * 32768; op = EW2T + (size_t)lyr * 32768;
    R = 64; C = 512; r0 = (lo & 1) * 32; c0 = (lo >> 1) * 32;
  }
#pragma unroll
  for (int i = 0; i < 4; ++i) {
    int r = r0 + threadIdx.y + i * 8;
    int c = c0 + threadIdx.x;
    float v = (r < R && c < C) ? ip[(size_t)r * C + c] : 0.f;
    t[threadIdx.x][threadIdx.y + i * 8] = f2b(v);
  }
  __syncthreads();
#pragma unroll
  for (int i = 0; i < 4; ++i) {
    int c = c0 + threadIdx.y + i * 8;
    int r = r0 + threadIdx.x;
    if (c < C && r < R) op[(size_t)c * R + r] = t[threadIdx.y + i * 8][threadIdx.x];
  }
}

// ---------------- bf16 transpose: in [R,C] -> out [C,R] ----------------
__global__ __launch_bounds__(256) void transpose_b16(const ushort* __restrict__ in,
    ushort* __restrict__ out, int R, int C) {
  __shared__ ushort t[32][33];
  const int r0 = blockIdx.x * 32, c0 = blockIdx.y * 32;
#pragma unroll
  for (int i = 0; i < 4; ++i)
    t[threadIdx.x][threadIdx.y + i * 8] = in[(size_t)(r0 + threadIdx.y + i * 8) * C + c0 + threadIdx.x];
  __syncthreads();
#pragma unroll
  for (int i = 0; i < 4; ++i)
    out[(size_t)(c0 + threadIdx.y + i * 8) * R + r0 + threadIdx.x] = t[threadIdx.y + i * 8][threadIdx.x];
}

// ---------------- LN(X + Y) over 512 features; writes f32 and/or bf16 ----------------
__global__ __launch_bounds__(256) void ln_add(const float* __restrict__ X,
    const float* __restrict__ Y, const float* __restrict__ g, const float* __restrict__ b,
    float* __restrict__ of, ushort* __restrict__ ob) {
  const int r = blockIdx.x, t = threadIdx.x;
  const size_t base = (size_t)r * 512;
  float v0 = X[base + t] + Y[base + t];
  float v1 = X[base + t + 256] + Y[base + t + 256];
  float s = v0 + v1;
#pragma unroll
  for (int o = 1; o < 64; o <<= 1) s += __shfl_xor(s, o);
  __shared__ float sm[4], sq[4];
  const int l = t & 63, w = t >> 6;
  if (l == 0) sm[w] = s;
  __syncthreads();
  const float mu = (sm[0] + sm[1] + sm[2] + sm[3]) * (1.f / 512.f);
  const float d0 = v0 - mu, d1 = v1 - mu;
  float q = d0 * d0 + d1 * d1;
#pragma unroll
  for (int o = 1; o < 64; o <<= 1) q += __shfl_xor(q, o);
  if (l == 0) sq[w] = q;
  __syncthreads();
  const float var = (sq[0] + sq[1] + sq[2] + sq[3]) * (1.f / 512.f);
  const float rs = rsqrtf(var + 1e-5f);
  const float o0 = d0 * rs * g[t] + b[t];
  const float o1 = d1 * rs * g[t + 256] + b[t + 256];
  if (of) { of[base + t] = o0; of[base + t + 256] = o1; }
  if (ob) { ob[base + t] = f2b(o0); ob[base + t + 256] = f2b(o1); }
}

extern "C" void kernel_launch(void* const* d_in, const int* in_sizes, int n_in,
                              void* d_out, int out_size, void* d_ws, size_t ws_size,
                              hipStream_t stream) {
  (void)in_sizes; (void)n_in; (void)out_size;
  const float* X1   = (const float*)d_in[0];
  const float* X2   = (const float*)d_in[1];
  const float* X3   = (const float*)d_in[2];
  const float* WQ   = (const float*)d_in[3];
  const float* WK   = (const float*)d_in[4];
  const float* WV   = (const float*)d_in[5];
  const float* WVB  = (const float*)d_in[6];
  const float* Wali = (const float*)d_in[7];
  const float* W_O  = (const float*)d_in[8];
  const float* eWq  = (const float*)d_in[9];
  const float* eWk  = (const float*)d_in[10];
  const float* eWv  = (const float*)d_in[11];
  const float* ebq  = (const float*)d_in[12];
  const float* ebk  = (const float*)d_in[13];
  const float* ebv  = (const float*)d_in[14];
  const float* eWo  = (const float*)d_in[15];
  const float* ebo  = (const float*)d_in[16];
  const float* eg1  = (const float*)d_in[17];
  const float* ebl1 = (const float*)d_in[18];
  const float* eW1  = (const float*)d_in[19];
  const float* eB1  = (const float*)d_in[20];
  const float* eW2  = (const float*)d_in[21];
  const float* eB2  = (const float*)d_in[22];
  const float* eg2  = (const float*)d_in[23];
  const float* ebl2 = (const float*)d_in[24];
  float* OUT = (float*)d_out;
  char* ws = (char*)d_ws;

  // ---- fixed workspace region ----
  const size_t oQB   = 0;                 // [2048,512] bf16
  const size_t oKB   = 2097152;
  const size_t oVB   = 4194304;           // [2048,512] bf16 (pre-transpose V)
  const size_t oVTB  = 6291456;           // [512,2048] bf16
  const size_t oZAB  = 8388608;           // [2048,768] bf16
  const size_t oWOT  = 11534336;          // [512,768]
  const size_t oEWQT = 12320768;          // [2*512,512] (EWQT..EWOT contiguous)
  const size_t oEWVT = 14417920;
  const size_t oEWOT = 15466496;
  const size_t oEW1T = 16515072;          // [2*64,512]
  const size_t oEW2T = 16646144;          // [2*512,64]
  const size_t oWVBT = 16777216;          // [256,1024]
  const size_t oZBT  = 17301504;          // [256,2048]
  const size_t oZ    = 18350080;          // phase A: XAb bf16 [2048,5120]; later Zf
  const size_t oZB16 = 22544384;          // [2048,512] bf16 (live from W_O on)
  const size_t oX2F  = 24641536;          // [2048,512] f32
  const size_t oX2B  = 28835840;          // bf16
  const size_t oY    = 30932992;          // [2048,512] f32
  const size_t oATT  = 35127296;          // [2048,512] bf16
  const size_t oPM   = 37486592;          // [128,2048] f32 (stats)
  const size_t oPS   = 38535168;
  const size_t oLSE  = 39583744;          // [8,2048] f32
  const size_t oDYN  = 39649280;          // phased arena (bf16 partials)
  const size_t oWQT  = oDYN;
  const size_t oQKVP = oDYN + 15728640;   // 5 x [2048,1536] bf16 = 31.5M (ends @ oDYN+47.2M)
  const size_t oZBP  = oDYN;
  const size_t oSX3  = oDYN;              // written AFTER phase-A partials consumed
  const size_t oWAB  = oDYN + 16777216;
  const size_t oW2P  = oDYN + 33554432;
  const size_t oW2T  = oDYN + 50331648;
  const size_t oZAP  = oDYN;              // 4 x [2048,512] bf16 = 8.4M (phase C)
  const size_t oSCFe = oDYN;              // encoder scores f32 [2048,2048] = 16.8M
  if (ws_size < oDYN + 67108864) return;  // 106.8 MB needed (121.5 MB proven available)

  ushort* XAb  = (ushort*)(ws + oZ);      // [2048,5120] bf16, dead after phase A
  ushort* WQT  = (ushort*)(ws + oWQT);    // combined [1536,5120] (WQ|WK|WV rows)
  ushort* QKVP = (ushort*)(ws + oQKVP);
  ushort* ZBP  = (ushort*)(ws + oZBP);
  ushort* sX3  = (ushort*)(ws + oSX3);
  ushort* Walib= (ushort*)(ws + oWAB);    // Wali bf16 [4096,2048] (native layout)
  ushort* W2P  = (ushort*)(ws + oW2P);
  ushort* W2Tb = (ushort*)(ws + oW2T);    // [256,4096] bf16
  ushort* ZBP2 = (ushort*)(ws + oW2P);    // reuse after W2 reduce
  ushort* ZAP  = (ushort*)(ws + oZAP);
  float*  SCFe = (float*)(ws + oSCFe);
  ushort* Qb   = (ushort*)(ws + oQB);
  ushort* Kb   = (ushort*)(ws + oKB);
  ushort* Vb   = (ushort*)(ws + oVB);
  ushort* Vtb  = (ushort*)(ws + oVTB);
  ushort* ZABb = (ushort*)(ws + oZAB);
  ushort* WOT  = (ushort*)(ws + oWOT);
  ushort* EWQT = (ushort*)(ws + oEWQT);
  ushort* EWVT = (ushort*)(ws + oEWVT);
  ushort* EWOT = (ushort*)(ws + oEWOT);
  ushort* EW1T = (ushort*)(ws + oEW1T);
  ushort* EW2T = (ushort*)(ws + oEW2T);
  ushort* WVBT = (ushort*)(ws + oWVBT);
  ushort* ZBT  = (ushort*)(ws + oZBT);
  float*  Zf   = (float*)(ws + oZ);
  ushort* Zb16 = (ushort*)(ws + oZB16);
  float*  X2f  = (float*)(ws + oX2F);
  ushort* X2b  = (ushort*)(ws + oX2B);
  float*  Yf   = (float*)(ws + oY);
  ushort* ATTb = (ushort*)(ws + oATT);
  float*  PM   = (float*)(ws + oPM);
  float*  PS   = (float*)(ws + oPS);
  float*  LSE  = (float*)(ws + oLSE);

  const dim3 tb(32, 8);
  const float rs512 = 0.044194173824159216f;  // 1/sqrt(512)

  // ---- phase 0: input concat + weight transposes (batched) ----
  prep_xab<<<2048, 256, 0, stream>>>(X1, X2, XAb);
  {
    PtrList wqkv; wqkv.p[0] = WQ; wqkv.p[1] = WK; wqkv.p[2] = WV; wqkv.p[3] = nullptr;
    transpose_conv_multi<<<dim3(160, 2, 24), tb, 0, stream>>>(wqkv, 8, WQT, 5120, 64);
    PtrList enc4; enc4.p[0] = eWq; enc4.p[1] = eWk; enc4.p[2] = eWv; enc4.p[3] = eWo;
    transpose_conv_multi<<<dim3(16, 16, 8), tb, 0, stream>>>(enc4, 2, EWQT, 512, 512);
  }
  transpose_conv_batch<<<768, tb, 0, stream>>>(WVB, WVBT, W_O, WOT, eW1, EW1T, eW2, EW2T);

  // ---- phase A: QKV projection (256^2 8-phase, SKX=5, bf16 partials) + zb ----
  // grid (6 colblocks x 5 k-chunks, 8 rowblocks) = 240 wg = 1 block/CU, 240%8==0.
  gemm256<6><<<dim3(30, 8, 1), 512, 0, stream>>>(
      XAb, 5120, WQT, 5120, QKVP, 1536, 3145728LL, 1024);
  reduceN<5,0><<<1024, 256, 0, stream>>>(QKVP, 3145728LL, Qb, 1536, 512, 0, 0,
      9, 1048576LL, 0.125f, 512, 2048, nullptr);
  transpose_b16<<<dim3(64, 16), tb, 0, stream>>>(Vb, Vtb, 2048, 512);
  gemm<64,64,0,0,false,true,4,false,false,1><<<dim3(128,4,1), 256, 0, stream>>>(
      WVBT, 1024, 0, XAb + 4096, 5120, 0, nullptr, ZBP, 2048, 524288LL,
      nullptr, nullptr, nullptr, nullptr, 1.f, 1.f, 256);
  reduceN<4,0><<<1024, 256, 0, stream>>>(ZBP, 524288LL, ZBT, 2048, 2048, 0, 0,
      30, 0, 1.f, 0, 256, nullptr);

  // ---- phase B: type-B via associativity (sX3/Walib written now: partials dead) ----
  prep_x3w<<<2048, 256, 0, stream>>>(X3, Wali, sX3, Walib);
  gemm<128,128,0,0,false,true,4,false,false,2><<<dim3(128,2,1), 256, 0, stream>>>(
      ZBT, 2048, 0, Walib, 2048, 0, nullptr, W2P, 4096, 1048576LL,
      nullptr, nullptr, nullptr, nullptr, 1.f, 1.f, 512);
  reduceN<4,0><<<512, 256, 0, stream>>>(W2P, 1048576LL, W2Tb, 4096, 4096, 0, 0,
      30, 0, 1.f, 0, 256, nullptr);
  gemm<128,64,0,0,false,true,8,false,false,1><<<dim3(32,16,1), 256, 0, stream>>>(
      sX3, 4096, 0, W2Tb, 4096, 0, nullptr, ZBP2, 256, 524288LL,
      nullptr, nullptr, nullptr, nullptr, 1.f, 1.f, 512);
  reduceN<8,0><<<512, 256, 0, stream>>>(ZBP2, 524288LL, ZABb + 512, 256, 768, 0, 0,
      30, 0, 1.f, 0, 2048, nullptr);

  // ---- phase C: type-A attention (stats pass -> LSE -> m-split fused PV -> reduce) ----
  gemm<128,64,0,0,false,false,1,true,false,1><<<dim3(32,16,8), 256, 0, stream>>>(
      Qb, 512, 64, Kb, 512, 64, nullptr, nullptr, 2048, 0,
      nullptr, nullptr, PM, PS, 1.f, 1.f, 64);
  colcombine<<<64, 256, 0, stream>>>(PM, PS, LSE);
  pv_fused<<<dim3(32, 4, 8), 256, 0, stream>>>(Qb, Kb, Vtb, LSE, ZAP);
  reduceN<4,0><<<1024, 256, 0, stream>>>(ZAP, 1048576LL, ZABb, 512, 768, 0, 0,
      30, 0, 1.f, 0, 2048, nullptr);

  // ---- W_O projection ----
  gemm<64,64,0,0,true,true,1,false,false,2><<<dim3(8,32,1), 256, 0, stream>>>(
      ZABb, 768, 0, WOT, 768, 0, Zf, Zb16, 512, 0,
      nullptr, nullptr, nullptr, nullptr, 1.f, 1.f, 768);

  // ---- 2 encoder layers ----
  for (int lyr = 0; lyr < 2; ++lyr) {
    const ushort* wq = EWQT + (size_t)lyr * 262144;
    const ushort* wv = EWVT + (size_t)lyr * 262144;
    const ushort* wo = EWOT + (size_t)lyr * 262144;
    const ushort* w1 = EW1T + (size_t)lyr * 32768;
    const ushort* w2 = EW2T + (size_t)lyr * 32768;
    gemm<128,64,1,0,false,true,1,false,false,2><<<dim3(8,16,2), 256, 0, stream>>>(
        Zb16, 512, 0, wq, 512, 524288LL, nullptr, Qb, 512, 1048576LL,
        ebq + lyr * 512, ebk + lyr * 512, nullptr, nullptr, rs512, 1.f, 512);
    gemm<64,64,2,0,false,true,1,false,false,2><<<dim3(32,8,1), 256, 0, stream>>>(
        wv, 512, 0, Zb16, 512, 0, nullptr, Vtb, 2048, 0,
        ebv + lyr * 512, nullptr, nullptr, nullptr, 1.f, 1.f, 512);
    gemm<128,64,0,0,true,false,1,false,true,1><<<dim3(32,16,1), 256, 0, stream>>>(
        Qb, 512, 0, Kb, 512, 0, SCFe, nullptr, 2048, 0,
        nullptr, nullptr, PM, PS, 1.f, 1.f, 512);
    rowcombine<<<8, 256, 0, stream>>>(PM, PS, LSE);
    attp_fused<<<dim3(8, 32), 256, 0, stream>>>(SCFe, LSE, Vtb, ATTb);
    gemm<64,64,1,0,true,false,1,false,false,2><<<dim3(8,32,1), 256, 0, stream>>>(
        ATTb, 512, 0, wo, 512, 0, Yf, nullptr, 512, 0,
        ebo + lyr * 512, nullptr, nullptr, nullptr, 1.f, 1.f, 512);
    ln_add<<<2048, 256, 0, stream>>>(Zf, Yf, eg1 + lyr * 512, ebl1 + lyr * 512, X2f, X2b);
    ffn_fused<<<dim3(8, 32), 256, 0, stream>>>(
        X2b, w1, eB1 + lyr * 64, w2, eB2 + lyr * 512, Yf);
    ln_add<<<2048, 256, 0, stream>>>(X2f, Yf, eg2 + lyr * 512, ebl2 + lyr * 512,
                                     (lyr == 0) ? Zf : OUT, (lyr == 0) ? Zb16 : nullptr);
  }
}

// Round 6
// 351.222 us; speedup vs baseline: 1.2381x; 1.2381x over previous
//
#include <hip/hip_runtime.h>

#define DEV __device__ __forceinline__

typedef __attribute__((ext_vector_type(4))) float f32x4;
typedef __attribute__((ext_vector_type(8))) short s16x8;

DEV ushort f2b(float f) {
  union { float f; unsigned u; } x; x.f = f;
  unsigned r = (x.u + 0x7FFFu + ((x.u >> 16) & 1u)) >> 16;
  return (ushort)r;
}
DEV float b2f(ushort u) {
  union { unsigned u; float f; } x; x.u = ((unsigned)u) << 16;
  return x.f;
}

DEV void gload16(const ushort* g, ushort* l) {
  __builtin_amdgcn_global_load_lds(
      (const __attribute__((address_space(1))) unsigned int*)g,
      (__attribute__((address_space(3))) unsigned int*)l, 16, 0, 0);
}

struct PtrList { const float* p[4]; };

// ---------------- GEMM: C[M,N] = act((A[M,K] @ B[N,K]^T + bias) * scale) ----------------
// bf16 K-major A,B. 256 threads, 4 waves (2x2), BK=64, XOR-swizzled LDS (conflict-free).
// XCD-bijective chunk remap, x-major decode (B-panel locality per XCD L2; verified R15).
// NBUF=2: double-buffered prefetch loop. NBUF=1: m97-style single-buffer 2-barrier loop.
// BIAS: 0 none, 1 per-col, 2 per-row. ACT: 0/1 relu. OF/OB both false = stats-only.
// SKX>1: x encodes {ks, colblock}; K = chunk len; bf16 partial slice (z*SKX+ks)*sC -> Cb.
// CSTAT/RSTAT: per-col / per-row max+sumexp of this block's f32 acc -> pmo/pso.
template<int BM, int BN, int BIAS, int ACT, bool OF, bool OB, int SKX,
         bool CSTAT, bool RSTAT, int NBUF>
__global__ __launch_bounds__(256) void gemm(
    const ushort* __restrict__ A, int lda, long long sA,
    const ushort* __restrict__ B, int ldb, long long sB,
    float* __restrict__ Cf, ushort* __restrict__ Cb, int ldc, long long sC,
    const float* __restrict__ bias, const float* __restrict__ bias2,
    float* __restrict__ pmo, float* __restrict__ pso,
    float scale0, float scale1, int K)
{
  constexpr int WM = BM / 2, WN = BN / 2, FM = WM / 16, FN = WN / 16;
  __shared__ __align__(16) ushort As[NBUF][BM * 64];
  __shared__ __align__(16) ushort Bs[NBUF][BN * 64];
  const int tid = threadIdx.x, l = tid & 63, w = tid >> 6;
  const int wr = w >> 1, wc = w & 1;
  const int gx = gridDim.x, gy = gridDim.y;
  const int nwg = gx * gy;
  const int orig = blockIdx.y * gx + blockIdx.x;
  const int xcd = orig & 7, rest = orig >> 3;
  const int q8 = nwg >> 3, r8 = nwg & 7;
  const int f = (xcd < r8 ? xcd * (q8 + 1) : r8 * (q8 + 1) + (xcd - r8) * q8) + rest;
  int bxr = f / gy;
  const int byy = f - bxr * gy;
  int ks = 0;
  if constexpr (SKX > 1) {
    const int nbx = gx / SKX;
    ks = bxr / nbx; bxr -= ks * nbx;
  }
  const int brow = byy * BM, bcol = bxr * BN;
  const long long z = blockIdx.z;
  A += z * sA + (size_t)ks * K;
  B += z * sB + (size_t)ks * K;
  const int lr = l & 15;
  const int sw = lr & 7, kh = l >> 4;
  f32x4 acc[FM][FN] = {};
  const int nk = K >> 6;

  auto stage = [&](int kt, int buf) {
    const int kof = kt << 6;
#pragma unroll
    for (int i = 0; i < BM / 32; ++i) {
      const int c = i * 256 + tid;            // LDS chunk: row=c>>3, slot k8=c&7
      const int r = c >> 3, k8 = c & 7;
      gload16(A + (size_t)(brow + r) * lda + kof + ((k8 ^ (r & 7)) << 3),
              &As[buf][i * 2048 + w * 512]);
    }
#pragma unroll
    for (int i = 0; i < BN / 32; ++i) {
      const int c = i * 256 + tid;
      const int r = c >> 3, k8 = c & 7;
      gload16(B + (size_t)(bcol + r) * ldb + kof + ((k8 ^ (r & 7)) << 3),
              &Bs[buf][i * 2048 + w * 512]);
    }
  };

  auto compute = [&](int kt, int buf) {
#pragma unroll
    for (int kk = 0; kk < 2; ++kk) {
      const int koff = ((kk * 4 + kh) ^ sw) << 3;   // swizzled 16B-chunk offset
      s16x8 af[FM], bf[FN];
#pragma unroll
      for (int m = 0; m < FM; ++m)
        af[m] = *(const s16x8*)&As[buf][(wr * WM + m * 16 + lr) * 64 + koff];
#pragma unroll
      for (int n = 0; n < FN; ++n)
        bf[n] = *(const s16x8*)&Bs[buf][(wc * WN + n * 16 + lr) * 64 + koff];
#pragma unroll
      for (int m = 0; m < FM; ++m)
#pragma unroll
        for (int n = 0; n < FN; ++n)
          acc[m][n] = __builtin_amdgcn_mfma_f32_16x16x32_bf16(af[m], bf[n], acc[m][n], 0, 0, 0);
    }
  };

  if constexpr (NBUF == 2) {
    stage(0, 0);
    __syncthreads();
    for (int kt = 0; kt < nk - 1; ++kt) {
      stage(kt + 1, (kt + 1) & 1);
      compute(kt, kt & 1);
      __syncthreads();
    }
    compute(nk - 1, (nk - 1) & 1);
  } else {
    for (int kt = 0; kt < nk; ++kt) {
      stage(kt, 0);
      __syncthreads();   // staging complete (drains vmcnt)
      compute(kt, 0);
      __syncthreads();   // reads complete; buffer reusable
    }
  }

  if constexpr (OF || OB) {
    const float sc = (z == 0) ? scale0 : scale1;
    const float* bp = (z == 0) ? bias : bias2;
    const int cr = (l >> 4) * 4, cc = l & 15;
#pragma unroll
    for (int m = 0; m < FM; ++m) {
      const int r0 = brow + wr * WM + m * 16 + cr;
#pragma unroll
      for (int n = 0; n < FN; ++n) {
        const int gc = bcol + wc * WN + n * 16 + cc;
        float bc = 0.f;
        if constexpr (BIAS == 1) bc = bp[gc];
#pragma unroll
        for (int j = 0; j < 4; ++j) {
          float v = acc[m][n][j];
          if constexpr (BIAS == 1) v += bc;
          if constexpr (BIAS == 2) v += bp[r0 + j];
          v *= sc;
          if constexpr (ACT == 1) v = fmaxf(v, 0.f);
          const size_t off = (size_t)(r0 + j) * ldc + gc + (size_t)((z * SKX + ks) * sC);
          if constexpr (OF) Cf[off] = v;
          if constexpr (OB) Cb[off] = f2b(v);
        }
      }
    }
  }

  if constexpr (CSTAT) {
    __shared__ float sM[2][2][FN][16], sS[2][2][FN][16];
    float mx[FN], se[FN];
#pragma unroll
    for (int n = 0; n < FN; ++n) {
      float m0 = -3e38f;
#pragma unroll
      for (int m = 0; m < FM; ++m)
#pragma unroll
        for (int j = 0; j < 4; ++j) m0 = fmaxf(m0, acc[m][n][j]);
      float s0 = 0.f;
#pragma unroll
      for (int m = 0; m < FM; ++m)
#pragma unroll
        for (int j = 0; j < 4; ++j) s0 += __expf(acc[m][n][j] - m0);
      mx[n] = m0; se[n] = s0;
    }
#pragma unroll
    for (int o = 16; o <= 32; o <<= 1) {
#pragma unroll
      for (int n = 0; n < FN; ++n) {
        float m2 = __shfl_xor(mx[n], o), s2 = __shfl_xor(se[n], o);
        float M = fmaxf(mx[n], m2);
        se[n] = se[n] * __expf(mx[n] - M) + s2 * __expf(m2 - M);
        mx[n] = M;
      }
    }
    __syncthreads();
    if (l < 16) {
#pragma unroll
      for (int n = 0; n < FN; ++n) { sM[wr][wc][n][l] = mx[n]; sS[wr][wc][n][l] = se[n]; }
    }
    __syncthreads();
    if (wr == 0 && l < 16) {
#pragma unroll
      for (int n = 0; n < FN; ++n) {
        float m1 = sM[0][wc][n][l], m2 = sM[1][wc][n][l];
        float s1 = sS[0][wc][n][l], s2 = sS[1][wc][n][l];
        float M = fmaxf(m1, m2);
        float S = s1 * __expf(m1 - M) + s2 * __expf(m2 - M);
        const int gc = bcol + wc * 32 + n * 16 + l;
        const size_t o = ((size_t)(z * gy + byy)) * 2048 + gc;
        pmo[o] = M; pso[o] = S;
      }
    }
  }

  if constexpr (RSTAT) {
    __shared__ float sRM[2][2][WM], sRS[2][2][WM];
#pragma unroll
    for (int m = 0; m < FM; ++m) {
#pragma unroll
      for (int j = 0; j < 4; ++j) {
        float m0 = -3e38f;
#pragma unroll
        for (int n = 0; n < FN; ++n) m0 = fmaxf(m0, acc[m][n][j]);
        float s0 = 0.f;
#pragma unroll
        for (int n = 0; n < FN; ++n) s0 += __expf(acc[m][n][j] - m0);
#pragma unroll
        for (int o = 1; o <= 8; o <<= 1) {
          float m2 = __shfl_xor(m0, o), s2 = __shfl_xor(s0, o);
          float M = fmaxf(m0, m2);
          s0 = s0 * __expf(m0 - M) + s2 * __expf(m2 - M);
          m0 = M;
        }
        if ((l & 15) == 0) {
          sRM[wr][wc][m * 16 + (l >> 4) * 4 + j] = m0;
          sRS[wr][wc][m * 16 + (l >> 4) * 4 + j] = s0;
        }
      }
    }
    __syncthreads();
    if (wc == 0) {
      float m1 = sRM[wr][0][l], m2 = sRM[wr][1][l];
      float s1 = sRS[wr][0][l], s2 = sRS[wr][1][l];
      float M = fmaxf(m1, m2);
      float S = s1 * __expf(m1 - M) + s2 * __expf(m2 - M);
      const size_t o = (size_t)bxr * 2048 + brow + wr * WM + l;
      pmo[o] = M; pso[o] = S;
    }
  }
}

// ================= 256x256 8-phase GEMM, read-ahead + compiler-scheduled waits ==========
// (R4 best variant, unchanged: 39.6-40.0 us, ~807 TF effective. Further schedule surgery
// shelved after 4 null results; MFMA floor at this shape/occupancy is ~16.6 us.)
template<int MH, int NH>
DEV void qmfma2(const s16x8 (&Ax)[8], const s16x8 (&Bf)[4], f32x4 (&acc)[8][4]) {
#pragma unroll
  for (int kk = 0; kk < 2; ++kk)
#pragma unroll
    for (int m = 0; m < 4; ++m)
#pragma unroll
      for (int n = 0; n < 2; ++n)
        acc[MH * 4 + m][NH * 2 + n] = __builtin_amdgcn_mfma_f32_16x16x32_bf16(
            Ax[kk * 4 + m], Bf[kk * 2 + n], acc[MH * 4 + m][NH * 2 + n], 0, 0, 0);
}

DEV void tailwait(int c) {
  if (c == 1) { asm volatile("s_waitcnt vmcnt(4)" ::: "memory"); }
  else if (c == 2) { asm volatile("s_waitcnt vmcnt(0)" ::: "memory"); }
}

#define GBAR() asm volatile("s_barrier" ::: "memory")

template<int NBX>
__global__ __launch_bounds__(512, 2) void gemm256(
    const ushort* __restrict__ A, int lda,
    const ushort* __restrict__ B, int ldb,
    ushort* __restrict__ Cb, int ldc, long long sC, int Kc)
{
  __shared__ __align__(16) ushort As[2][2][8192];   // [buf][half][128*64]
  __shared__ __align__(16) ushort Bs[2][2][8192];
  const int tid = threadIdx.x, l = tid & 63, w = tid >> 6;
  const int wr = w >> 2, wc = w & 3;
  const int gx = gridDim.x, gy = gridDim.y;
  const int nwg = gx * gy;
  const int orig = blockIdx.y * gx + blockIdx.x;
  const int xcd = orig & 7, rest = orig >> 3;
  const int q8 = nwg >> 3, r8 = nwg & 7;
  const int f = (xcd < r8 ? xcd * (q8 + 1) : r8 * (q8 + 1) + (xcd - r8) * q8) + rest;
  int bxr = f / gy;
  const int byy = f - bxr * gy;
  const int ks = bxr / NBX; bxr -= ks * NBX;
  const int brow = byy * 256, bcol = bxr * 256;
  A += (size_t)ks * Kc;
  B += (size_t)ks * Kc;
  const int nk = Kc >> 6;
  const int lr = l & 15, kh = l >> 4, sw = lr & 7;
  const int arow = wr * 64 + lr, brw = wc * 32 + lr;

  // staging: chunk c = i*512+tid; i=0 -> rows 0..63 of the half, i=1 -> rows 64..127
  const int r0 = tid >> 3, k80 = tid & 7;
  const size_t aoff = (size_t)(brow + r0) * lda + ((k80 ^ (r0 & 7)) << 3);
  const size_t boff = (size_t)(bcol + r0) * ldb + ((k80 ^ (r0 & 7)) << 3);

  f32x4 acc[8][4] = {};
  s16x8 Ax[8];              // active A-half fragments (single slot)
  s16x8 B0s[4], B1s[4];     // B-half fragments, both halves of active buffer

  auto stA = [&](int kt, int buf, int half) {
    if (kt >= nk) return;
    const ushort* s = A + aoff + (size_t)(half * 128) * lda + (kt << 6);
    gload16(s, &As[buf][half][w * 512]);
    gload16(s + (size_t)64 * lda, &As[buf][half][4096 + w * 512]);
  };
  auto stB = [&](int kt, int buf, int half) {
    if (kt >= nk) return;
    const ushort* s = B + boff + (size_t)(half * 128) * ldb + (kt << 6);
    gload16(s, &Bs[buf][half][w * 512]);
    gload16(s + (size_t)64 * ldb, &Bs[buf][half][4096 + w * 512]);
  };
  auto rdA = [&](int buf, int half) {
#pragma unroll
    for (int kk = 0; kk < 2; ++kk) {
      const int koff = ((kk * 4 + kh) ^ sw) << 3;
#pragma unroll
      for (int m = 0; m < 4; ++m)
        Ax[kk * 4 + m] = *(const s16x8*)&As[buf][half][(arow + m * 16) * 64 + koff];
    }
  };
  auto rdB = [&](s16x8 (&dst)[4], int buf, int half) {
#pragma unroll
    for (int kk = 0; kk < 2; ++kk) {
      const int koff = ((kk * 4 + kh) ^ sw) << 3;
#pragma unroll
      for (int n = 0; n < 2; ++n)
        dst[kk * 2 + n] = *(const s16x8*)&Bs[buf][half][(brw + n * 16) * 64 + koff];
    }
  };

  // prologue: tile0 {A0,B0,A1,B1} -> buf0; tile1 {A0,B0} -> buf1 (12 loads)
  stA(0, 0, 0); stB(0, 0, 0); stA(0, 0, 1); stB(0, 0, 1);
  stA(1, 1, 0); stB(1, 1, 0);
  asm volatile("s_waitcnt vmcnt(4)" ::: "memory");   // tile0 landed; tile1 A0/B0 in flight
  GBAR();
  rdA(0, 0); rdB(B0s, 0, 0);                          // frags for P1 of iter 0

  const int NT2 = nk >> 1;
#pragma unroll 1
  for (int j = 0; j < NT2; ++j) {
    const int tb = 2 * j + 1, ta2 = 2 * j + 2, tb2 = 2 * j + 3;
    const bool more = (ta2 < nk);
    // P1: MFMA(A0,B0)@buf0; read-ahead B1@buf0 under the MFMA
    stA(tb, 1, 1); GBAR();
    rdB(B1s, 0, 1);
    __builtin_amdgcn_s_setprio(1); qmfma2<0, 0>(Ax, B0s, acc); __builtin_amdgcn_s_setprio(0);
    GBAR();
    // P2: MFMA(A0,B1)
    stB(tb, 1, 1); GBAR();
    __builtin_amdgcn_s_setprio(1); qmfma2<0, 1>(Ax, B1s, acc); __builtin_amdgcn_s_setprio(0);
    GBAR();
    // P3: in-phase A-half1 read, then MFMA(A1,B0)
    stA(ta2, 0, 0); GBAR();
    rdA(0, 1);
    __builtin_amdgcn_s_setprio(1); qmfma2<1, 0>(Ax, B0s, acc); __builtin_amdgcn_s_setprio(0);
    GBAR();
    // P4: MFMA(A1,B1); counted vmcnt; then GAP reads of b's A0/B0 (all-waves safe)
    stB(ta2, 0, 0); GBAR();
    __builtin_amdgcn_s_setprio(1); qmfma2<1, 1>(Ax, B1s, acc); __builtin_amdgcn_s_setprio(0);
    tailwait(more ? 1 : 2); GBAR();
    rdA(1, 0); rdB(B0s, 1, 0);
    // P5: MFMA(A0,B0)@buf1; read-ahead B1@buf1
    stA(ta2, 0, 1); GBAR();
    rdB(B1s, 1, 1);
    __builtin_amdgcn_s_setprio(1); qmfma2<0, 0>(Ax, B0s, acc); __builtin_amdgcn_s_setprio(0);
    GBAR();
    // P6: MFMA(A0,B1)
    stB(ta2, 0, 1); GBAR();
    __builtin_amdgcn_s_setprio(1); qmfma2<0, 1>(Ax, B1s, acc); __builtin_amdgcn_s_setprio(0);
    GBAR();
    // P7: in-phase A-half1 read, then MFMA(A1,B0)
    stA(tb2, 1, 0); GBAR();
    rdA(1, 1);
    __builtin_amdgcn_s_setprio(1); qmfma2<1, 0>(Ax, B0s, acc); __builtin_amdgcn_s_setprio(0);
    GBAR();
    // P8: MFMA(A1,B1); counted vmcnt; GAP reads of (a+2)'s A0/B0 for next P1
    stB(tb2, 1, 0); GBAR();
    __builtin_amdgcn_s_setprio(1); qmfma2<1, 1>(Ax, B1s, acc); __builtin_amdgcn_s_setprio(0);
    tailwait(more ? 1 : 0); GBAR();
    if (more) { rdA(0, 0); rdB(B0s, 0, 0); }
  }

  // epilogue: bf16 partial slice ks
  ushort* out = Cb + (size_t)ks * sC;
  const int cr = kh * 4, cc = lr;
#pragma unroll
  for (int mh = 0; mh < 2; ++mh)
#pragma unroll
    for (int m = 0; m < 4; ++m) {
      const int ro = brow + mh * 128 + wr * 64 + m * 16 + cr;
#pragma unroll
      for (int nh = 0; nh < 2; ++nh)
#pragma unroll
        for (int n = 0; n < 2; ++n) {
          const int gc = bcol + nh * 128 + wc * 32 + n * 16 + cc;
#pragma unroll
          for (int j2 = 0; j2 < 4; ++j2)
            out[(size_t)(ro + j2) * ldc + gc] = f2b(acc[mh * 4 + m][nh * 2 + n][j2]);
        }
    }
}

// ---------------- fused FFN: Y[r, bx*64+c] = relu(X@W1^T+b1) @ W2chunk^T + b2 ----------
// grid (8 out-col chunks, 32 row blocks), 256 thr, 64x64 tiles, 4 waves (2x2).
// H kept in LDS with the stage-compatible XOR swizzle; f32 accumulation throughout.
__global__ __launch_bounds__(256) void ffn_fused(
    const ushort* __restrict__ X, const ushort* __restrict__ W1,
    const float* __restrict__ b1, const ushort* __restrict__ W2T,
    const float* __restrict__ b2, float* __restrict__ Y)
{
  __shared__ __align__(16) ushort As[64 * 64];
  __shared__ __align__(16) ushort Bs[64 * 64];
  __shared__ __align__(16) ushort Hs[64 * 64];
  const int tid = threadIdx.x, l = tid & 63, w = tid >> 6;
  const int wr = w >> 1, wc = w & 1;
  const int bx = blockIdx.x, brow = blockIdx.y * 64;
  const int lr = l & 15, g = l >> 4, sw = lr & 7;
  f32x4 acc[2][2] = {};
  // phase 1: H = relu(X[64,512] @ W1[64,512]^T + b1)
  for (int kt = 0; kt < 8; ++kt) {
    const int kof = kt << 6;
#pragma unroll
    for (int i = 0; i < 2; ++i) {
      const int c = i * 256 + tid, r = c >> 3, k8 = c & 7;
      gload16(X + (size_t)(brow + r) * 512 + kof + ((k8 ^ (r & 7)) << 3),
              &As[i * 2048 + w * 512]);
    }
#pragma unroll
    for (int i = 0; i < 2; ++i) {
      const int c = i * 256 + tid, r = c >> 3, k8 = c & 7;
      gload16(W1 + (size_t)r * 512 + kof + ((k8 ^ (r & 7)) << 3),
              &Bs[i * 2048 + w * 512]);
    }
    __syncthreads();
#pragma unroll
    for (int kk = 0; kk < 2; ++kk) {
      const int koff = ((kk * 4 + g) ^ sw) << 3;
      s16x8 af[2], bf[2];
#pragma unroll
      for (int m = 0; m < 2; ++m) af[m] = *(const s16x8*)&As[(wr * 32 + m * 16 + lr) * 64 + koff];
#pragma unroll
      for (int n = 0; n < 2; ++n) bf[n] = *(const s16x8*)&Bs[(wc * 32 + n * 16 + lr) * 64 + koff];
#pragma unroll
      for (int m = 0; m < 2; ++m)
#pragma unroll
        for (int n = 0; n < 2; ++n)
          acc[m][n] = __builtin_amdgcn_mfma_f32_16x16x32_bf16(af[m], bf[n], acc[m][n], 0, 0, 0);
    }
    __syncthreads();
  }
  // epilogue1: bias+relu -> Hs (swizzled: content[row][s] = H[row][col], s=(col>>3)^(row&7))
#pragma unroll
  for (int m = 0; m < 2; ++m)
#pragma unroll
    for (int n = 0; n < 2; ++n) {
      const int col = wc * 32 + n * 16 + lr;
      const float bb = b1[col];
#pragma unroll
      for (int j = 0; j < 4; ++j) {
        const int row = wr * 32 + m * 16 + g * 4 + j;
        Hs[row * 64 + (((col >> 3) ^ (row & 7)) << 3) + (col & 7)] =
            f2b(fmaxf(acc[m][n][j] + bb, 0.f));
      }
    }
  // stage W2 chunk (Bs free after the final loop barrier)
#pragma unroll
  for (int i = 0; i < 2; ++i) {
    const int c = i * 256 + tid, r = c >> 3, k8 = c & 7;
    gload16(W2T + (size_t)(bx * 64 + r) * 64 + ((k8 ^ (r & 7)) << 3),
            &Bs[i * 2048 + w * 512]);
  }
  __syncthreads();
  // phase 2: Y = H @ W2chunk^T + b2 (K=64)
  f32x4 acc2[2][2] = {};
#pragma unroll
  for (int kk = 0; kk < 2; ++kk) {
    const int koff = ((kk * 4 + g) ^ sw) << 3;
    s16x8 af[2], bf[2];
#pragma unroll
    for (int m = 0; m < 2; ++m) af[m] = *(const s16x8*)&Hs[(wr * 32 + m * 16 + lr) * 64 + koff];
#pragma unroll
    for (int n = 0; n < 2; ++n) bf[n] = *(const s16x8*)&Bs[(wc * 32 + n * 16 + lr) * 64 + koff];
#pragma unroll
    for (int m = 0; m < 2; ++m)
#pragma unroll
      for (int n = 0; n < 2; ++n)
        acc2[m][n] = __builtin_amdgcn_mfma_f32_16x16x32_bf16(af[m], bf[n], acc2[m][n], 0, 0, 0);
  }
#pragma unroll
  for (int m = 0; m < 2; ++m)
#pragma unroll
    for (int n = 0; n < 2; ++n) {
      const int gc = bx * 64 + wc * 32 + n * 16 + lr;
      const float bb = b2[gc];
#pragma unroll
      for (int j = 0; j < 4; ++j) {
        const int row = brow + wr * 32 + m * 16 + g * 4 + j;
        Y[(size_t)row * 512 + gc] = acc2[m][n][j] + bb;
      }
    }
}

// ---------------- fused type-A PV, m-split x4: bf16 partial ZA over 8 m-chunks ----------
__global__ __launch_bounds__(256) void pv_fused(
    const ushort* __restrict__ Q, const ushort* __restrict__ K,
    const ushort* __restrict__ Vt, const float* __restrict__ lse,
    ushort* __restrict__ ZAP)
{
  __shared__ __align__(16) ushort Qs[64 * 64];
  __shared__ __align__(16) ushort Ks[2][64 * 64];
  __shared__ __align__(16) ushort Vs[2][64 * 64];
  __shared__ __align__(16) ushort Ps[64 * 64];
  __shared__ float Ls[512];
  const int tid = threadIdx.x, l = tid & 63, w = tid >> 6;
  const int wr = w >> 1, wc = w & 1;
  const int h = blockIdx.z, brow = blockIdx.x * 64, ms = blockIdx.y;
  const int lr = l & 15, g = l >> 4, sw = lr & 7;

  auto stageKV = [&](int mc, int buf) {
#pragma unroll
    for (int i = 0; i < 2; ++i) {
      const int c = i * 256 + tid, r = c >> 3, k8 = c & 7;
      gload16(K + (size_t)(mc * 64 + r) * 512 + h * 64 + ((k8 ^ (r & 7)) << 3),
              &Ks[buf][i * 2048 + w * 512]);
    }
#pragma unroll
    for (int i = 0; i < 2; ++i) {
      const int c = i * 256 + tid, r = c >> 3, k8 = c & 7;
      gload16(Vt + (size_t)(h * 64 + r) * 2048 + mc * 64 + ((k8 ^ (r & 7)) << 3),
              &Vs[buf][i * 2048 + w * 512]);
    }
  };

#pragma unroll
  for (int i = 0; i < 2; ++i) {
    const int c = i * 256 + tid, r = c >> 3, k8 = c & 7;
    gload16(Q + (size_t)(brow + r) * 512 + h * 64 + ((k8 ^ (r & 7)) << 3),
            &Qs[i * 2048 + w * 512]);
  }
  stageKV(ms * 8, 0);
  for (int i = tid; i < 512; i += 256) Ls[i] = lse[h * 2048 + ms * 512 + i];
  __syncthreads();

  s16x8 aq[2][2];
#pragma unroll
  for (int nf = 0; nf < 2; ++nf)
#pragma unroll
    for (int kk = 0; kk < 2; ++kk)
      aq[nf][kk] = *(const s16x8*)&Qs[(wr * 32 + nf * 16 + lr) * 64 + (((kk * 4 + g) ^ sw) << 3)];

  f32x4 zacc[2][2] = {};
  for (int mi = 0; mi < 8; ++mi) {
    const int mc = ms * 8 + mi;
    const int buf = mi & 1;
    if (mi < 7) stageKV(mc + 1, buf ^ 1);
    f32x4 sacc[2][2] = {};
#pragma unroll
    for (int kk = 0; kk < 2; ++kk) {
      const int koff = ((kk * 4 + g) ^ sw) << 3;
      s16x8 bk[2];
#pragma unroll
      for (int mf = 0; mf < 2; ++mf)
        bk[mf] = *(const s16x8*)&Ks[buf][(wc * 32 + mf * 16 + lr) * 64 + koff];
#pragma unroll
      for (int nf = 0; nf < 2; ++nf)
#pragma unroll
        for (int mf = 0; mf < 2; ++mf)
          sacc[nf][mf] = __builtin_amdgcn_mfma_f32_16x16x32_bf16(aq[nf][kk], bk[mf], sacc[nf][mf], 0, 0, 0);
    }
#pragma unroll
    for (int nf = 0; nf < 2; ++nf)
#pragma unroll
      for (int mf = 0; mf < 2; ++mf) {
        const int m_loc = wc * 32 + mf * 16 + lr;
        const float lv = Ls[mi * 64 + m_loc];
#pragma unroll
        for (int j = 0; j < 4; ++j) {
          const int n_loc = wr * 32 + nf * 16 + g * 4 + j;
          Ps[n_loc * 64 + (((m_loc >> 3) ^ (n_loc & 7)) << 3) + (m_loc & 7)] =
              f2b(__expf(sacc[nf][mf][j] - lv));
        }
      }
    __syncthreads();  // P complete (also drains KV prefetch)
#pragma unroll
    for (int kk = 0; kk < 2; ++kk) {
      const int koff = ((kk * 4 + g) ^ sw) << 3;
      s16x8 pa[2], bv[2];
#pragma unroll
      for (int nf = 0; nf < 2; ++nf)
        pa[nf] = *(const s16x8*)&Ps[(wr * 32 + nf * 16 + lr) * 64 + koff];
#pragma unroll
      for (int vf = 0; vf < 2; ++vf)
        bv[vf] = *(const s16x8*)&Vs[buf][(wc * 32 + vf * 16 + lr) * 64 + koff];
#pragma unroll
      for (int nf = 0; nf < 2; ++nf)
#pragma unroll
        for (int vf = 0; vf < 2; ++vf)
          zacc[nf][vf] = __builtin_amdgcn_mfma_f32_16x16x32_bf16(pa[nf], bv[vf], zacc[nf][vf], 0, 0, 0);
    }
    __syncthreads();
  }
  ushort* out = ZAP + (size_t)ms * 2048 * 512;
#pragma unroll
  for (int nf = 0; nf < 2; ++nf)
#pragma unroll
    for (int vf = 0; vf < 2; ++vf)
#pragma unroll
      for (int j = 0; j < 4; ++j) {
        const int n = brow + wr * 32 + nf * 16 + g * 4 + j;
        const int col = h * 64 + wc * 32 + vf * 16 + lr;
        out[(size_t)n * 512 + col] = f2b(zacc[nf][vf][j]);
      }
}

// ------- split-K reduce: sum NS bf16 slices (f32 accum) -> bf16; optional bias+relu -----
template<int NS, int ACT>
__global__ __launch_bounds__(256) void reduceN(const ushort* __restrict__ P, long long sC,
    ushort* __restrict__ out, int cols, int ldout, long long zPoff, long long zOoff,
    int cshift, long long bstride, float scale, int scThresh, int rows,
    const float* __restrict__ bias)
{
  P += blockIdx.z * zPoff; out += blockIdx.z * zOoff;
  const int c4n = cols >> 2;
  const size_t total = (size_t)rows * c4n;
  for (size_t i = (size_t)blockIdx.x * 256 + threadIdx.x; i < total; i += (size_t)gridDim.x * 256) {
    const size_t r = i / c4n;
    const int c4 = (int)(i - r * c4n) << 2;
    float4 s = make_float4(0.f, 0.f, 0.f, 0.f);
#pragma unroll
    for (int k = 0; k < NS; ++k) {
      ushort4 t = *(const ushort4*)(P + (size_t)k * sC + r * cols + c4);
      s.x += b2f(t.x); s.y += b2f(t.y); s.z += b2f(t.z); s.w += b2f(t.w);
    }
    if constexpr (ACT == 1) {
      float4 bb = *(const float4*)(bias + c4);
      s.x = fmaxf(s.x + bb.x, 0.f); s.y = fmaxf(s.y + bb.y, 0.f);
      s.z = fmaxf(s.z + bb.z, 0.f); s.w = fmaxf(s.w + bb.w, 0.f);
    }
    const float sc = (c4 < scThresh) ? scale : 1.f;
    ushort4 o;
    o.x = f2b(s.x * sc); o.y = f2b(s.y * sc); o.z = f2b(s.z * sc); o.w = f2b(s.w * sc);
    const size_t oo = r * ldout + (size_t)(c4 >> cshift) * bstride + (c4 & ((1 << cshift) - 1));
    *(ushort4*)(out + oo) = o;
  }
}

// ---------------- prep A: XAb = bf16(X1|X2) (phase 0) ----------------
__global__ __launch_bounds__(256) void prep_xab(const float* __restrict__ X1,
    const float* __restrict__ X2, ushort* __restrict__ XAb) {
  const size_t total = (size_t)2048 * 1280;       // ushort4 units (5120/4)
  for (size_t i = (size_t)blockIdx.x * 256 + threadIdx.x; i < total; i += (size_t)gridDim.x * 256) {
    const size_t r = i / 1280;
    const int c = (int)(i - r * 1280) << 2;
    float4 v = (c < 4096) ? *(const float4*)(X1 + r * 4096 + c)
                          : *(const float4*)(X2 + r * 1024 + (c - 4096));
    ushort4 o; o.x = f2b(v.x); o.y = f2b(v.y); o.z = f2b(v.z); o.w = f2b(v.w);
    *(ushort4*)(XAb + r * 5120 + c) = o;
  }
}

// ---- prep B: sX3 = bf16(sigmoid(X3)); Walib = bf16(Wali). MUST run after phase-A
//      partials (QKVP/ZBP, which overlap these arena spans) are consumed. ----
__global__ __launch_bounds__(256) void prep_x3w(const float* __restrict__ X3,
    const float* __restrict__ Wali, ushort* __restrict__ sX3,
    ushort* __restrict__ Walib) {
  const size_t n1 = (size_t)2048 * 1024;          // sX3 (4096/4)
  const size_t n2 = (size_t)4096 * 512;           // Walib (2048/4)
  const size_t total = n1 + n2;
  for (size_t i = (size_t)blockIdx.x * 256 + threadIdx.x; i < total; i += (size_t)gridDim.x * 256) {
    if (i < n1) {
      const size_t r = i / 1024;
      const int c = (int)(i - r * 1024) << 2;
      float4 v = *(const float4*)(X3 + r * 4096 + c);
      v.x = 1.f / (1.f + __expf(-v.x)); v.y = 1.f / (1.f + __expf(-v.y));
      v.z = 1.f / (1.f + __expf(-v.z)); v.w = 1.f / (1.f + __expf(-v.w));
      ushort4 o; o.x = f2b(v.x); o.y = f2b(v.y); o.z = f2b(v.z); o.w = f2b(v.w);
      *(ushort4*)(sX3 + r * 4096 + c) = o;
    } else {
      const size_t j = i - n1;
      const size_t r = j / 512;
      const int c = (int)(j - r * 512) << 2;
      float4 v = *(const float4*)(Wali + r * 2048 + c);
      ushort4 o; o.x = f2b(v.x); o.y = f2b(v.y); o.z = f2b(v.z); o.w = f2b(v.w);
      *(ushort4*)(Walib + r * 2048 + c) = o;
    }
  }
}

// ---------------- P = exp(S - LSE[row]) with inline LSE from col-block stats ------------
__global__ __launch_bounds__(256) void expconv_row(const float* __restrict__ S,
    const float* __restrict__ pm, const float* __restrict__ ps, ushort* __restrict__ P) {
  const int r = blockIdx.x;
  float m = pm[(size_t)(threadIdx.x & 31) * 2048 + r];
  float s = ps[(size_t)(threadIdx.x & 31) * 2048 + r];
#pragma unroll
  for (int o = 1; o < 32; o <<= 1) {
    float m2 = __shfl_xor(m, o), s2 = __shfl_xor(s, o);
    float M = fmaxf(m, m2);
    s = s * __expf(m - M) + s2 * __expf(m2 - M);
    m = M;
  }
  const float L = m + __logf(s);
  const float* row = S + (size_t)r * 2048;
  ushort* pr = P + (size_t)r * 2048;
  for (int c = threadIdx.x * 4; c < 2048; c += 1024) {
    float4 v = *(const float4*)(row + c);
    ushort4 o4;
    o4.x = f2b(__expf(v.x - L)); o4.y = f2b(__expf(v.y - L));
    o4.z = f2b(__expf(v.z - L)); o4.w = f2b(__expf(v.w - L));
    *(ushort4*)(pr + c) = o4;
  }
}

__global__ __launch_bounds__(256) void colcombine(const float* __restrict__ pm,
    const float* __restrict__ ps, float* __restrict__ lse) {
  const int id = blockIdx.x * 256 + threadIdx.x;  // h*2048 + c
  const int h = id >> 11, c = id & 2047;
  float M = -3e38f;
#pragma unroll
  for (int s = 0; s < 16; ++s) M = fmaxf(M, pm[((size_t)(h * 16 + s)) * 2048 + c]);
  float S = 0.f;
#pragma unroll
  for (int s = 0; s < 16; ++s) {
    size_t o = ((size_t)(h * 16 + s)) * 2048 + c;
    S += ps[o] * __expf(pm[o] - M);
  }
  lse[id] = M + __logf(S);
}

// ---------------- multi-tensor transpose_conv: z selects tensor (z/zPerT) + slice --------
__global__ __launch_bounds__(256) void transpose_conv_multi(PtrList in, int zPerT,
    ushort* __restrict__ out, int R, int C) {
  __shared__ ushort t[32][33];
  const int z = blockIdx.z;
  const float* ip = in.p[z / zPerT] + (size_t)(z % zPerT) * R * C;
  ushort* op = out + (size_t)z * R * C;
  const int r0 = blockIdx.x * 32, c0 = blockIdx.y * 32;
#pragma unroll
  for (int i = 0; i < 4; ++i) {
    int r = r0 + threadIdx.y + i * 8;
    int c = c0 + threadIdx.x;
    float v = (r < R && c < C) ? ip[(size_t)r * C + c] : 0.f;
    t[threadIdx.x][threadIdx.y + i * 8] = f2b(v);
  }
  __syncthreads();
#pragma unroll
  for (int i = 0; i < 4; ++i) {
    int c = c0 + threadIdx.y + i * 8;
    int r = r0 + threadIdx.x;
    if (c < C && r < R) op[(size_t)c * R + r] = t[threadIdx.y + i * 8][threadIdx.x];
  }
}

// ---------------- batched small transposes: WVB, W_O, eW1, eW2 in one launch ------------
__global__ __launch_bounds__(256) void transpose_conv_batch(
    const float* __restrict__ WVB, ushort* __restrict__ WVBT,
    const float* __restrict__ W_O, ushort* __restrict__ WOT,
    const float* __restrict__ eW1, ushort* __restrict__ EW1T,
    const float* __restrict__ eW2, ushort* __restrict__ EW2T) {
  __shared__ ushort t[32][33];
  const int b = blockIdx.x;
  const float* ip; ushort* op; int R, C, r0, c0;
  if (b < 256) {
    const int h = b >> 6, loc = b & 63;
    ip = WVB + (size_t)h * 65536; op = WVBT + (size_t)h * 65536;
    R = 1024; C = 64; r0 = (loc & 31) * 32; c0 = (loc >> 5) * 32;
  } else if (b < 640) {
    const int loc = b - 256;
    ip = W_O; op = WOT;
    R = 768; C = 512; r0 = (loc % 24) * 32; c0 = (loc / 24) * 32;
  } else if (b < 704) {
    const int loc = b - 640, lyr = loc >> 5, lo = loc & 31;
    ip = eW1 + (size_t)lyr * 32768; op = EW1T + (size_t)lyr * 32768;
    R = 512; C = 64; r0 = (lo & 15) * 32; c0 = (lo >> 4) * 32;
  } else {
    const int loc = b - 704, lyr = loc >> 5, lo = loc & 31;
    ip = eW2 + (size_t)lyr * 32768; op = EW2T + (size_t)lyr * 32768;
    R = 64; C = 512; r0 = (lo & 1) * 32; c0 = (lo >> 1) * 32;
  }
#pragma unroll
  for (int i = 0; i < 4; ++i) {
    int r = r0 + threadIdx.y + i * 8;
    int c = c0 + threadIdx.x;
    float v = (r < R && c < C) ? ip[(size_t)r * C + c] : 0.f;
    t[threadIdx.x][threadIdx.y + i * 8] = f2b(v);
  }
  __syncthreads();
#pragma unroll
  for (int i = 0; i < 4; ++i) {
    int c = c0 + threadIdx.y + i * 8;
    int r = r0 + threadIdx.x;
    if (c < C && r < R) op[(size_t)c * R + r] = t[threadIdx.y + i * 8][threadIdx.x];
  }
}

// ---------------- bf16 transpose: in [R,C] -> out [C,R] ----------------
__global__ __launch_bounds__(256) void transpose_b16(const ushort* __restrict__ in,
    ushort* __restrict__ out, int R, int C) {
  __shared__ ushort t[32][33];
  const int r0 = blockIdx.x * 32, c0 = blockIdx.y * 32;
#pragma unroll
  for (int i = 0; i < 4; ++i)
    t[threadIdx.x][threadIdx.y + i * 8] = in[(size_t)(r0 + threadIdx.y + i * 8) * C + c0 + threadIdx.x];
  __syncthreads();
#pragma unroll
  for (int i = 0; i < 4; ++i)
    out[(size_t)(c0 + threadIdx.y + i * 8) * R + r0 + threadIdx.x] = t[threadIdx.y + i * 8][threadIdx.x];
}

// ---------------- LN(X + Y) over 512 features; writes f32 and/or bf16 ----------------
__global__ __launch_bounds__(256) void ln_add(const float* __restrict__ X,
    const float* __restrict__ Y, const float* __restrict__ g, const float* __restrict__ b,
    float* __restrict__ of, ushort* __restrict__ ob) {
  const int r = blockIdx.x, t = threadIdx.x;
  const size_t base = (size_t)r * 512;
  float v0 = X[base + t] + Y[base + t];
  float v1 = X[base + t + 256] + Y[base + t + 256];
  float s = v0 + v1;
#pragma unroll
  for (int o = 1; o < 64; o <<= 1) s += __shfl_xor(s, o);
  __shared__ float sm[4], sq[4];
  const int l = t & 63, w = t >> 6;
  if (l == 0) sm[w] = s;
  __syncthreads();
  const float mu = (sm[0] + sm[1] + sm[2] + sm[3]) * (1.f / 512.f);
  const float d0 = v0 - mu, d1 = v1 - mu;
  float q = d0 * d0 + d1 * d1;
#pragma unroll
  for (int o = 1; o < 64; o <<= 1) q += __shfl_xor(q, o);
  if (l == 0) sq[w] = q;
  __syncthreads();
  const float var = (sq[0] + sq[1] + sq[2] + sq[3]) * (1.f / 512.f);
  const float rs = rsqrtf(var + 1e-5f);
  const float o0 = d0 * rs * g[t] + b[t];
  const float o1 = d1 * rs * g[t + 256] + b[t + 256];
  if (of) { of[base + t] = o0; of[base + t + 256] = o1; }
  if (ob) { ob[base + t] = f2b(o0); ob[base + t + 256] = f2b(o1); }
}

extern "C" void kernel_launch(void* const* d_in, const int* in_sizes, int n_in,
                              void* d_out, int out_size, void* d_ws, size_t ws_size,
                              hipStream_t stream) {
  (void)in_sizes; (void)n_in; (void)out_size;
  const float* X1   = (const float*)d_in[0];
  const float* X2   = (const float*)d_in[1];
  const float* X3   = (const float*)d_in[2];
  const float* WQ   = (const float*)d_in[3];
  const float* WK   = (const float*)d_in[4];
  const float* WV   = (const float*)d_in[5];
  const float* WVB  = (const float*)d_in[6];
  const float* Wali = (const float*)d_in[7];
  const float* W_O  = (const float*)d_in[8];
  const float* eWq  = (const float*)d_in[9];
  const float* eWk  = (const float*)d_in[10];
  const float* eWv  = (const float*)d_in[11];
  const float* ebq  = (const float*)d_in[12];
  const float* ebk  = (const float*)d_in[13];
  const float* ebv  = (const float*)d_in[14];
  const float* eWo  = (const float*)d_in[15];
  const float* ebo  = (const float*)d_in[16];
  const float* eg1  = (const float*)d_in[17];
  const float* ebl1 = (const float*)d_in[18];
  const float* eW1  = (const float*)d_in[19];
  const float* eB1  = (const float*)d_in[20];
  const float* eW2  = (const float*)d_in[21];
  const float* eB2  = (const float*)d_in[22];
  const float* eg2  = (const float*)d_in[23];
  const float* ebl2 = (const float*)d_in[24];
  float* OUT = (float*)d_out;
  char* ws = (char*)d_ws;

  // ---- fixed workspace region ----
  const size_t oQB   = 0;                 // [2048,512] bf16
  const size_t oKB   = 2097152;
  const size_t oVB   = 4194304;           // [2048,512] bf16 (pre-transpose V)
  const size_t oVTB  = 6291456;           // [512,2048] bf16
  const size_t oZAB  = 8388608;           // [2048,768] bf16
  const size_t oWOT  = 11534336;          // [512,768]
  const size_t oEWQT = 12320768;          // [2*512,512] (EWQT..EWOT contiguous)
  const size_t oEWVT = 14417920;
  const size_t oEWOT = 15466496;
  const size_t oEW1T = 16515072;          // [2*64,512]
  const size_t oEW2T = 16646144;          // [2*512,64]
  const size_t oWVBT = 16777216;          // [256,1024]
  const size_t oZBT  = 17301504;          // [256,2048]
  const size_t oZ    = 18350080;          // phase A: XAb bf16 [2048,5120]; later Zf
  const size_t oZB16 = 22544384;          // [2048,512] bf16 (live from W_O on)
  const size_t oX2F  = 24641536;          // [2048,512] f32
  const size_t oX2B  = 28835840;          // bf16
  const size_t oY    = 30932992;          // [2048,512] f32
  const size_t oATT  = 35127296;          // [2048,512] bf16
  const size_t oPM   = 37486592;          // [128,2048] f32 (stats)
  const size_t oPS   = 38535168;
  const size_t oLSE  = 39583744;          // [8,2048] f32
  const size_t oDYN  = 39649280;          // phased arena (bf16 partials)
  const size_t oWQT  = oDYN;
  const size_t oQKVP = oDYN + 15728640;   // 5 x [2048,1536] bf16 = 31.5M (ends @ oDYN+47.2M)
  const size_t oZBP  = oDYN;
  const size_t oSX3  = oDYN;              // written AFTER phase-A partials consumed
  const size_t oWAB  = oDYN + 16777216;
  const size_t oW2P  = oDYN + 33554432;
  const size_t oW2T  = oDYN + 50331648;
  const size_t oZAP  = oDYN;              // 4 x [2048,512] bf16 = 8.4M (phase C)
  const size_t oSCFe = oDYN;
  const size_t oPbe  = oDYN + 16777216;
  const size_t oATTP = oDYN + 50331648;
  if (ws_size < oDYN + 67108864) return;  // 106.8 MB needed (121.5 MB proven available)

  ushort* XAb  = (ushort*)(ws + oZ);      // [2048,5120] bf16, dead after phase A
  ushort* WQT  = (ushort*)(ws + oWQT);    // combined [1536,5120] (WQ|WK|WV rows)
  ushort* QKVP = (ushort*)(ws + oQKVP);
  ushort* ZBP  = (ushort*)(ws + oZBP);
  ushort* sX3  = (ushort*)(ws + oSX3);
  ushort* Walib= (ushort*)(ws + oWAB);    // Wali bf16 [4096,2048] (native layout)
  ushort* W2P  = (ushort*)(ws + oW2P);
  ushort* W2Tb = (ushort*)(ws + oW2T);    // [256,4096] bf16
  ushort* ZBP2 = (ushort*)(ws + oW2P);    // reuse after W2 reduce
  ushort* ZAP  = (ushort*)(ws + oZAP);
  float*  SCFe = (float*)(ws + oSCFe);
  ushort* Pbe  = (ushort*)(ws + oPbe);
  ushort* ATTP = (ushort*)(ws + oATTP);
  ushort* Qb   = (ushort*)(ws + oQB);
  ushort* Kb   = (ushort*)(ws + oKB);
  ushort* Vb   = (ushort*)(ws + oVB);
  ushort* Vtb  = (ushort*)(ws + oVTB);
  ushort* ZABb = (ushort*)(ws + oZAB);
  ushort* WOT  = (ushort*)(ws + oWOT);
  ushort* EWQT = (ushort*)(ws + oEWQT);
  ushort* EWVT = (ushort*)(ws + oEWVT);
  ushort* EWOT = (ushort*)(ws + oEWOT);
  ushort* EW1T = (ushort*)(ws + oEW1T);
  ushort* EW2T = (ushort*)(ws + oEW2T);
  ushort* WVBT = (ushort*)(ws + oWVBT);
  ushort* ZBT  = (ushort*)(ws + oZBT);
  float*  Zf   = (float*)(ws + oZ);
  ushort* Zb16 = (ushort*)(ws + oZB16);
  float*  X2f  = (float*)(ws + oX2F);
  ushort* X2b  = (ushort*)(ws + oX2B);
  float*  Yf   = (float*)(ws + oY);
  ushort* ATTb = (ushort*)(ws + oATT);
  float*  PM   = (float*)(ws + oPM);
  float*  PS   = (float*)(ws + oPS);
  float*  LSE  = (float*)(ws + oLSE);

  const dim3 tb(32, 8);
  const float rs512 = 0.044194173824159216f;  // 1/sqrt(512)

  // ---- phase 0: input concat + weight transposes (batched) ----
  prep_xab<<<2048, 256, 0, stream>>>(X1, X2, XAb);
  {
    PtrList wqkv; wqkv.p[0] = WQ; wqkv.p[1] = WK; wqkv.p[2] = WV; wqkv.p[3] = nullptr;
    transpose_conv_multi<<<dim3(160, 2, 24), tb, 0, stream>>>(wqkv, 8, WQT, 5120, 64);
    PtrList enc4; enc4.p[0] = eWq; enc4.p[1] = eWk; enc4.p[2] = eWv; enc4.p[3] = eWo;
    transpose_conv_multi<<<dim3(16, 16, 8), tb, 0, stream>>>(enc4, 2, EWQT, 512, 512);
  }
  transpose_conv_batch<<<768, tb, 0, stream>>>(WVB, WVBT, W_O, WOT, eW1, EW1T, eW2, EW2T);

  // ---- phase A: QKV projection (256^2 8-phase, SKX=5, bf16 partials) + zb ----
  // grid (6 colblocks x 5 k-chunks, 8 rowblocks) = 240 wg = 1 block/CU, 240%8==0.
  gemm256<6><<<dim3(30, 8, 1), 512, 0, stream>>>(
      XAb, 5120, WQT, 5120, QKVP, 1536, 3145728LL, 1024);
  reduceN<5,0><<<1024, 256, 0, stream>>>(QKVP, 3145728LL, Qb, 1536, 512, 0, 0,
      9, 1048576LL, 0.125f, 512, 2048, nullptr);
  transpose_b16<<<dim3(64, 16), tb, 0, stream>>>(Vb, Vtb, 2048, 512);
  gemm<64,64,0,0,false,true,4,false,false,1><<<dim3(128,4,1), 256, 0, stream>>>(
      WVBT, 1024, 0, XAb + 4096, 5120, 0, nullptr, ZBP, 2048, 524288LL,
      nullptr, nullptr, nullptr, nullptr, 1.f, 1.f, 256);
  reduceN<4,0><<<1024, 256, 0, stream>>>(ZBP, 524288LL, ZBT, 2048, 2048, 0, 0,
      30, 0, 1.f, 0, 256, nullptr);

  // ---- phase B: type-B via associativity (sX3/Walib written now: partials dead) ----
  prep_x3w<<<2048, 256, 0, stream>>>(X3, Wali, sX3, Walib);
  gemm<128,128,0,0,false,true,4,false,false,2><<<dim3(128,2,1), 256, 0, stream>>>(
      ZBT, 2048, 0, Walib, 2048, 0, nullptr, W2P, 4096, 1048576LL,
      nullptr, nullptr, nullptr, nullptr, 1.f, 1.f, 512);
  reduceN<4,0><<<512, 256, 0, stream>>>(W2P, 1048576LL, W2Tb, 4096, 4096, 0, 0,
      30, 0, 1.f, 0, 256, nullptr);
  gemm<128,64,0,0,false,true,8,false,false,1><<<dim3(32,16,1), 256, 0, stream>>>(
      sX3, 4096, 0, W2Tb, 4096, 0, nullptr, ZBP2, 256, 524288LL,
      nullptr, nullptr, nullptr, nullptr, 1.f, 1.f, 512);
  reduceN<8,0><<<512, 256, 0, stream>>>(ZBP2, 524288LL, ZABb + 512, 256, 768, 0, 0,
      30, 0, 1.f, 0, 2048, nullptr);

  // ---- phase C: type-A attention (stats pass -> LSE -> m-split fused PV -> reduce) ----
  gemm<128,64,0,0,false,false,1,true,false,1><<<dim3(32,16,8), 256, 0, stream>>>(
      Qb, 512, 64, Kb, 512, 64, nullptr, nullptr, 2048, 0,
      nullptr, nullptr, PM, PS, 1.f, 1.f, 64);
  colcombine<<<64, 256, 0, stream>>>(PM, PS, LSE);
  pv_fused<<<dim3(32, 4, 8), 256, 0, stream>>>(Qb, Kb, Vtb, LSE, ZAP);
  reduceN<4,0><<<1024, 256, 0, stream>>>(ZAP, 1048576LL, ZABb, 512, 768, 0, 0,
      30, 0, 1.f, 0, 2048, nullptr);

  // ---- W_O projection ----
  gemm<64,64,0,0,true,true,1,false,false,2><<<dim3(8,32,1), 256, 0, stream>>>(
      ZABb, 768, 0, WOT, 768, 0, Zf, Zb16, 512, 0,
      nullptr, nullptr, nullptr, nullptr, 1.f, 1.f, 768);

  // ---- 2 encoder layers ----
  for (int lyr = 0; lyr < 2; ++lyr) {
    const ushort* wq = EWQT + (size_t)lyr * 262144;
    const ushort* wv = EWVT + (size_t)lyr * 262144;
    const ushort* wo = EWOT + (size_t)lyr * 262144;
    const ushort* w1 = EW1T + (size_t)lyr * 32768;
    const ushort* w2 = EW2T + (size_t)lyr * 32768;
    gemm<128,64,1,0,false,true,1,false,false,2><<<dim3(8,16,2), 256, 0, stream>>>(
        Zb16, 512, 0, wq, 512, 524288LL, nullptr, Qb, 512, 1048576LL,
        ebq + lyr * 512, ebk + lyr * 512, nullptr, nullptr, rs512, 1.f, 512);
    gemm<64,64,2,0,false,true,1,false,false,2><<<dim3(32,8,1), 256, 0, stream>>>(
        wv, 512, 0, Zb16, 512, 0, nullptr, Vtb, 2048, 0,
        ebv + lyr * 512, nullptr, nullptr, nullptr, 1.f, 1.f, 512);
    gemm<128,64,0,0,true,false,1,false,true,1><<<dim3(32,16,1), 256, 0, stream>>>(
        Qb, 512, 0, Kb, 512, 0, SCFe, nullptr, 2048, 0,
        nullptr, nullptr, PM, PS, 1.f, 1.f, 512);
    expconv_row<<<2048, 256, 0, stream>>>(SCFe, PM, PS, Pbe);
    gemm<128,64,0,0,false,true,4,false,false,1><<<dim3(32,16,1), 256, 0, stream>>>(
        Pbe, 2048, 0, Vtb, 2048, 0, nullptr, ATTP, 512, 1048576LL,
        nullptr, nullptr, nullptr, nullptr, 1.f, 1.f, 512);
    reduceN<4,0><<<1024, 256, 0, stream>>>(ATTP, 1048576LL, ATTb, 512, 512, 0, 0,
        30, 0, 1.f, 0, 2048, nullptr);
    gemm<64,64,1,0,true,false,1,false,false,2><<<dim3(8,32,1), 256, 0, stream>>>(
        ATTb, 512, 0, wo, 512, 0, Yf, nullptr, 512, 0,
        ebo + lyr * 512, nullptr, nullptr, nullptr, 1.f, 1.f, 512);
    ln_add<<<2048, 256, 0, stream>>>(Zf, Yf, eg1 + lyr * 512, ebl1 + lyr * 512, X2f, X2b);
    ffn_fused<<<dim3(8, 32), 256, 0, stream>>>(
        X2b, w1, eB1 + lyr * 64, w2, eB2 + lyr * 512, Yf);
    ln_add<<<2048, 256, 0, stream>>>(X2f, Yf, eg2 + lyr * 512, ebl2 + lyr * 512,
                                     (lyr == 0) ? Zf : OUT, (lyr == 0) ? Zb16 : nullptr);
  }
}